// Round 2
// baseline (565.517 us; speedup 1.0000x reference)
//
#include <hip/hip_runtime.h>
#include <stdint.h>

// FastAttention on MI355X (gfx950).
// Folded algebra:
//   q = x@Wq ; gq[b,d] = sum_n q*softmax_d(q*alpha*scale)
//   k = x@Wk ; p = gq*k ; gk[b,d] = sum_n p*softmax_d(p*beta*scale)
//   out[b] = x[b] @ (Wv @ diag(gk_b) @ Wr + Wq)     <- v / kv never materialized
// GEMM core: 128x128 tile, BK=64, XOR-swizzled LDS (pre-swizzled global src,
// rule #21), XCD-aware block swizzle (T1). bf16 MFMA 16x16x32, fp32 accum.

#define NBATCH 8
#define SEQ 4096
#define KD 768               // DIM == DEC == 768
#define ROWS (NBATCH * SEQ)  // 32768

typedef __bf16 bf16x8 __attribute__((ext_vector_type(8)));
typedef float f32x4 __attribute__((ext_vector_type(4)));

__device__ __forceinline__ unsigned short f2bf(float f) {
    __bf16 h = (__bf16)f;
    return __builtin_bit_cast(unsigned short, h);
}

__device__ __forceinline__ void gload16(const void* g, void* l) {
    __builtin_amdgcn_global_load_lds((const __attribute__((address_space(1))) void*)g,
                                     (__attribute__((address_space(3))) void*)l, 16, 0, 0);
}

// ---------- conversions ----------

__global__ __launch_bounds__(256) void cvt_f32_bf16x8(const float* __restrict__ src,
                                                      unsigned short* __restrict__ dst, int n8) {
    int i = blockIdx.x * 256 + threadIdx.x;
    if (i >= n8) return;
    const float4* p = (const float4*)src + (size_t)i * 2;
    float4 a = p[0], b = p[1];
    union { unsigned short s[8]; uint4 u; } t;
    t.s[0] = f2bf(a.x); t.s[1] = f2bf(a.y); t.s[2] = f2bf(a.z); t.s[3] = f2bf(a.w);
    t.s[4] = f2bf(b.x); t.s[5] = f2bf(b.y); t.s[6] = f2bf(b.z); t.s[7] = f2bf(b.w);
    ((uint4*)dst)[i] = t.u;
}

// WT[n][k] = bf16(W[k][n]) — 32x32 LDS tile transpose, grid (24,24)
__global__ __launch_bounds__(256) void transpose_to_bf16(const float* __restrict__ W,
                                                         unsigned short* __restrict__ WT) {
    __shared__ float tile[32][33];
    int tx = threadIdx.x & 31, tg = threadIdx.x >> 5;
    int bi = blockIdx.x * 32, bj = blockIdx.y * 32;
#pragma unroll
    for (int j = 0; j < 4; ++j) {
        int r = tg * 4 + j;
        tile[r][tx] = W[(size_t)(bi + r) * KD + bj + tx];
    }
    __syncthreads();
#pragma unroll
    for (int j = 0; j < 4; ++j) {
        int r = tg * 4 + j;
        WT[(size_t)(bj + r) * KD + bi + tx] = f2bf(tile[tx][r]);
    }
}

// ---------- GEMM core: 128x128 tile, BK=64 (128B rows), swizzled LDS ----------
// A: [M][768] bf16 row-major. B: [N][768] bf16 row-major (B^T of math B).
// LDS logical (row, c-byte in [0,128)) stored at byte row*128 + (c ^ ((row&7)<<4)).
// global_load_lds dest is linear; the XOR is applied to the GLOBAL source col
// (16B granule, stays within the same 128B line -> still fully coalesced).

__device__ __forceinline__ void gemm_tile_bk64(const unsigned short* __restrict__ A,
                                               const unsigned short* __restrict__ B,
                                               int m0, int n0, short* sA, short* sB,
                                               f32x4 acc[4][4]) {
    const int tid = threadIdx.x;
    const int lane = tid & 63;
    const int hi = lane >> 4;
    const int wr = (tid >> 7) & 1, wc = (tid >> 6) & 1;
    const f32x4 zero = {0.f, 0.f, 0.f, 0.f};
#pragma unroll
    for (int m = 0; m < 4; ++m)
#pragma unroll
        for (int n = 0; n < 4; ++n) acc[m][n] = zero;

    // staging: s-th chunk adds 32 rows (4096B/128B) -> row&7 unchanged -> same XOR
    {
        // base thread mapping for s=0
    }
    const int o0 = tid * 16;
    const int srow = o0 >> 7, scb = o0 & 127;
    const int sc = scb ^ ((srow & 7) << 4);  // inverse-swizzled source col
    const char* pA0 = (const char*)A + (size_t)(m0 + srow) * (KD * 2) + sc;
    const char* pB0 = (const char*)B + (size_t)(n0 + srow) * (KD * 2) + sc;
    char* lA0 = (char*)sA + o0;
    char* lB0 = (char*)sB + o0;
    const size_t sstep = (size_t)32 * (KD * 2);  // +32 rows per 4KB LDS chunk

    // fragment LDS byte offsets (swizzled read side)
    int offA[4][2], offB[4][2];
#pragma unroll
    for (int m = 0; m < 4; ++m) {
        int rowa = wr * 64 + m * 16 + (lane & 15);
        int rowb = wc * 64 + m * 16 + (lane & 15);
        int swa = (rowa & 7) << 4, swb = (rowb & 7) << 4;
#pragma unroll
        for (int kk = 0; kk < 2; ++kk) {
            offA[m][kk] = rowa * 128 + ((kk * 64 + hi * 16) ^ swa);
            offB[m][kk] = rowb * 128 + ((kk * 64 + hi * 16) ^ swb);
        }
    }

    for (int kt = 0; kt < KD * 2; kt += 128) {  // 12 iterations
        __syncthreads();
#pragma unroll
        for (int s = 0; s < 4; ++s) gload16(pA0 + s * sstep + kt, lA0 + s * 4096);
#pragma unroll
        for (int s = 0; s < 4; ++s) gload16(pB0 + s * sstep + kt, lB0 + s * 4096);
        __syncthreads();
#pragma unroll
        for (int kk = 0; kk < 2; ++kk) {
            bf16x8 af[4], bv[4];
#pragma unroll
            for (int m = 0; m < 4; ++m) af[m] = *(const bf16x8*)((const char*)sA + offA[m][kk]);
#pragma unroll
            for (int n = 0; n < 4; ++n) bv[n] = *(const bf16x8*)((const char*)sB + offB[n][kk]);
#pragma unroll
            for (int m = 0; m < 4; ++m)
#pragma unroll
                for (int n = 0; n < 4; ++n)
                    acc[m][n] = __builtin_amdgcn_mfma_f32_16x16x32_bf16(af[m], bv[n], acc[m][n], 0, 0, 0);
        }
    }
}

// T1: bijective XCD swizzle (nwg % 8 == 0 in all uses)
__device__ __forceinline__ int xcd_swz(int bid, int nwg) {
    int cpx = nwg >> 3;
    return (bid & 7) * cpx + (bid >> 3);
}

// C/D layout (m89): col = lane&15, row = (lane>>4)*4 + reg

__global__ __launch_bounds__(256) void gemm_bf16(const unsigned short* __restrict__ A,
                                                 const unsigned short* __restrict__ B,
                                                 unsigned short* __restrict__ C) {
    __shared__ short sA[128 * 64];
    __shared__ short sB[128 * 64];
    f32x4 acc[4][4];
    int wg = xcd_swz(blockIdx.y * gridDim.x + blockIdx.x, gridDim.x * gridDim.y);
    const int m0 = (wg / gridDim.x) * 128, n0 = (wg % gridDim.x) * 128;
    gemm_tile_bk64(A, B, m0, n0, sA, sB, acc);
    const int lane = threadIdx.x & 63;
    const int wr = (threadIdx.x >> 7) & 1, wc = (threadIdx.x >> 6) & 1;
    const int r0 = m0 + wr * 64 + ((lane >> 4) * 4);
    const int c0 = n0 + wc * 64 + (lane & 15);
#pragma unroll
    for (int m = 0; m < 4; ++m)
#pragma unroll
        for (int n = 0; n < 4; ++n)
#pragma unroll
            for (int r = 0; r < 4; ++r)
                C[(size_t)(r0 + m * 16 + r) * KD + (c0 + n * 16)] = f2bf(acc[m][n][r]);
}

// W3T_b[e][i] = bf16( sum_d WrS_b[e][d]*Wv[i][d] + Wq[i][e] ), grid (6,6,8)
__global__ __launch_bounds__(256) void gemm_w3(const unsigned short* __restrict__ WrS,
                                               const unsigned short* __restrict__ Wvb,
                                               const float* __restrict__ Wq,
                                               unsigned short* __restrict__ W3T) {
    __shared__ short sA[128 * 64];
    __shared__ short sB[128 * 64];
    f32x4 acc[4][4];
    const int b = blockIdx.z;
    const unsigned short* A = WrS + (size_t)b * (KD * KD);
    unsigned short* out = W3T + (size_t)b * (KD * KD);
    const int m0 = blockIdx.y * 128, n0 = blockIdx.x * 128;
    gemm_tile_bk64(A, Wvb, m0, n0, sA, sB, acc);
    const int lane = threadIdx.x & 63;
    const int wr = (threadIdx.x >> 7) & 1, wc = (threadIdx.x >> 6) & 1;
    const int r0 = m0 + wr * 64 + ((lane >> 4) * 4);
    const int c0 = n0 + wc * 64 + (lane & 15);
#pragma unroll
    for (int m = 0; m < 4; ++m)
#pragma unroll
        for (int n = 0; n < 4; ++n)
#pragma unroll
            for (int r = 0; r < 4; ++r) {
                int row = r0 + m * 16 + r, col = c0 + n * 16;
                out[(size_t)row * KD + col] = f2bf(acc[m][n][r] + Wq[(size_t)col * KD + row]);
            }
}

// out[row][e] = sum_i xb[row][i] * W3T_b[e][i], fp32 out, grid (6,256)
__global__ __launch_bounds__(256) void gemm_out_f32(const unsigned short* __restrict__ xb,
                                                    const unsigned short* __restrict__ W3T,
                                                    float* __restrict__ out) {
    __shared__ short sA[128 * 64];
    __shared__ short sB[128 * 64];
    f32x4 acc[4][4];
    int wg = xcd_swz(blockIdx.y * gridDim.x + blockIdx.x, gridDim.x * gridDim.y);
    const int bx = wg % gridDim.x, by = wg / gridDim.x;
    const int m0 = by * 128, n0 = bx * 128;
    const unsigned short* B = W3T + (size_t)(by >> 5) * (KD * KD);  // 32 m-tiles/batch
    gemm_tile_bk64(xb, B, m0, n0, sA, sB, acc);
    const int lane = threadIdx.x & 63;
    const int wr = (threadIdx.x >> 7) & 1, wc = (threadIdx.x >> 6) & 1;
    const int r0 = m0 + wr * 64 + ((lane >> 4) * 4);
    const int c0 = n0 + wc * 64 + (lane & 15);
#pragma unroll
    for (int m = 0; m < 4; ++m)
#pragma unroll
        for (int n = 0; n < 4; ++n)
#pragma unroll
            for (int r = 0; r < 4; ++r)
                out[(size_t)(r0 + m * 16 + r) * KD + (c0 + n * 16)] = acc[m][n][r];
}

// ---------- softmax-weighted reductions (1 wave per row group; lane owns 12 of 768 d) ----------

#define SM_SCALE 0.03608439182435161f  // 768^-0.5

__device__ __forceinline__ void unpack12(const unsigned short* rowp, int lane, float* q) {
    uint4 u = *(const uint4*)(rowp + lane * 8);
    uint2 v = *(const uint2*)(rowp + 512 + lane * 4);
    q[0] = __uint_as_float(u.x << 16);  q[1] = __uint_as_float(u.x & 0xffff0000u);
    q[2] = __uint_as_float(u.y << 16);  q[3] = __uint_as_float(u.y & 0xffff0000u);
    q[4] = __uint_as_float(u.z << 16);  q[5] = __uint_as_float(u.z & 0xffff0000u);
    q[6] = __uint_as_float(u.w << 16);  q[7] = __uint_as_float(u.w & 0xffff0000u);
    q[8] = __uint_as_float(v.x << 16);  q[9] = __uint_as_float(v.x & 0xffff0000u);
    q[10] = __uint_as_float(v.y << 16); q[11] = __uint_as_float(v.y & 0xffff0000u);
}

__device__ __forceinline__ void load12f(const float* base, int lane, float* o) {
    const float4* p0 = (const float4*)(base + lane * 8);
    float4 x0 = p0[0], x1 = p0[1];
    float4 x2 = *(const float4*)(base + 512 + lane * 4);
    o[0] = x0.x; o[1] = x0.y; o[2] = x0.z; o[3] = x0.w;
    o[4] = x1.x; o[5] = x1.y; o[6] = x1.z; o[7] = x1.w;
    o[8] = x2.x; o[9] = x2.y; o[10] = x2.z; o[11] = x2.w;
}

// grid (64, NBATCH): block handles 64 rows (4 waves x 16 rows)
__global__ __launch_bounds__(256) void reduce_gq(const unsigned short* __restrict__ qb,
                                                 const float* __restrict__ alpha,
                                                 float* __restrict__ gq) {
    const int b = blockIdx.y;
    const int lane = threadIdx.x & 63, wave = threadIdx.x >> 6;
    float al[12];
    load12f(alpha, lane, al);
    float acc[12];
#pragma unroll
    for (int j = 0; j < 12; ++j) acc[j] = 0.f;
    const int row0 = b * SEQ + blockIdx.x * 64 + wave * 16;
#pragma unroll 2
    for (int rr = 0; rr < 16; ++rr) {
        const unsigned short* rowp = qb + (size_t)(row0 + rr) * KD;
        float q[12], t[12];
        unpack12(rowp, lane, q);
        float mx = -1e30f;
#pragma unroll
        for (int j = 0; j < 12; ++j) { t[j] = q[j] * al[j] * SM_SCALE; mx = fmaxf(mx, t[j]); }
#pragma unroll
        for (int s = 32; s > 0; s >>= 1) mx = fmaxf(mx, __shfl_xor(mx, s));
        float sum = 0.f, e[12];
#pragma unroll
        for (int j = 0; j < 12; ++j) { e[j] = __expf(t[j] - mx); sum += e[j]; }
#pragma unroll
        for (int s = 32; s > 0; s >>= 1) sum += __shfl_xor(sum, s);
        float inv = 1.f / sum;
#pragma unroll
        for (int j = 0; j < 12; ++j) acc[j] += q[j] * e[j] * inv;
    }
    float* g = gq + b * KD;
#pragma unroll
    for (int j = 0; j < 8; ++j) atomicAdd(&g[lane * 8 + j], acc[j]);
#pragma unroll
    for (int j = 0; j < 4; ++j) atomicAdd(&g[512 + lane * 4 + j], acc[8 + j]);
}

__global__ __launch_bounds__(256) void reduce_gk(const unsigned short* __restrict__ kb,
                                                 const float* __restrict__ gq,
                                                 const float* __restrict__ beta,
                                                 float* __restrict__ gk) {
    const int b = blockIdx.y;
    const int lane = threadIdx.x & 63, wave = threadIdx.x >> 6;
    float bt[12], gv[12];
    load12f(beta, lane, bt);
    load12f(gq + b * KD, lane, gv);
    float acc[12];
#pragma unroll
    for (int j = 0; j < 12; ++j) acc[j] = 0.f;
    const int row0 = b * SEQ + blockIdx.x * 64 + wave * 16;
#pragma unroll 2
    for (int rr = 0; rr < 16; ++rr) {
        const unsigned short* rowp = kb + (size_t)(row0 + rr) * KD;
        float k[12], p[12], t[12];
        unpack12(rowp, lane, k);
        float mx = -1e30f;
#pragma unroll
        for (int j = 0; j < 12; ++j) {
            p[j] = gv[j] * k[j];
            t[j] = p[j] * bt[j] * SM_SCALE;
            mx = fmaxf(mx, t[j]);
        }
#pragma unroll
        for (int s = 32; s > 0; s >>= 1) mx = fmaxf(mx, __shfl_xor(mx, s));
        float sum = 0.f, e[12];
#pragma unroll
        for (int j = 0; j < 12; ++j) { e[j] = __expf(t[j] - mx); sum += e[j]; }
#pragma unroll
        for (int s = 32; s > 0; s >>= 1) sum += __shfl_xor(sum, s);
        float inv = 1.f / sum;
#pragma unroll
        for (int j = 0; j < 12; ++j) acc[j] += p[j] * e[j] * inv;
    }
    float* g = gk + b * KD;
#pragma unroll
    for (int j = 0; j < 8; ++j) atomicAdd(&g[lane * 8 + j], acc[j]);
#pragma unroll
    for (int j = 0; j < 4; ++j) atomicAdd(&g[512 + lane * 4 + j], acc[8 + j]);
}

// WrS[b][e][d] = bf16(WrT[e][d] * gk[b][d]); 8 elems/thread, grid 2304
__global__ __launch_bounds__(256) void scale_wr(const unsigned short* __restrict__ WrT,
                                                const float* __restrict__ gk,
                                                unsigned short* __restrict__ WrS) {
    int i = blockIdx.x * 256 + threadIdx.x;  // < 8*73728
    const int per = (KD * KD) / 8;           // 73728
    int b = i / per, g = i % per;
    int d = (g % (KD / 8)) * 8;
    uint4 w = *((const uint4*)WrT + g);
    const float* gkb = gk + b * KD + d;
    float4 s0 = *(const float4*)gkb;
    float4 s1 = *((const float4*)gkb + 1);
    union { unsigned short s[8]; uint4 u; } o;
    o.s[0] = f2bf(__uint_as_float(w.x << 16) * s0.x);
    o.s[1] = f2bf(__uint_as_float(w.x & 0xffff0000u) * s0.y);
    o.s[2] = f2bf(__uint_as_float(w.y << 16) * s0.z);
    o.s[3] = f2bf(__uint_as_float(w.y & 0xffff0000u) * s0.w);
    o.s[4] = f2bf(__uint_as_float(w.z << 16) * s1.x);
    o.s[5] = f2bf(__uint_as_float(w.z & 0xffff0000u) * s1.y);
    o.s[6] = f2bf(__uint_as_float(w.w << 16) * s1.z);
    o.s[7] = f2bf(__uint_as_float(w.w & 0xffff0000u) * s1.w);
    ((uint4*)WrS)[i] = o.u;
}

// ---------- launch ----------

extern "C" void kernel_launch(void* const* d_in, const int* in_sizes, int n_in,
                              void* d_out, int out_size, void* d_ws, size_t ws_size,
                              hipStream_t stream) {
    const float* x     = (const float*)d_in[0];
    const float* Wq    = (const float*)d_in[1];
    const float* Wk    = (const float*)d_in[2];
    const float* Wv    = (const float*)d_in[3];
    const float* Wr    = (const float*)d_in[4];
    const float* alpha = (const float*)d_in[5];
    const float* beta  = (const float*)d_in[6];
    float* out = (float*)d_out;
    char* ws = (char*)d_ws;

    // workspace layout (bytes), total ~124.3 MB (unchanged from passing R1)
    unsigned short* xb  = (unsigned short*)(ws);              // 50,331,648
    unsigned short* qk  = (unsigned short*)(ws + 50331648);   // 50,331,648 (q then reused for k)
    unsigned short* WqT = (unsigned short*)(ws + 100663296);  // 1,179,648
    unsigned short* WkT = (unsigned short*)(ws + 101842944);  // 1,179,648
    unsigned short* WrT = (unsigned short*)(ws + 103022592);  // 1,179,648
    unsigned short* Wvb = (unsigned short*)(ws + 104202240);  // 1,179,648
    unsigned short* WrS = (unsigned short*)(ws + 105381888);  // 9,437,184
    unsigned short* W3T = (unsigned short*)(ws + 114819072);  // 9,437,184
    float* gq = (float*)(ws + 124256256);                     // 24,576
    float* gk = (float*)(ws + 124280832);                     // 24,576

    hipMemsetAsync(gq, 0, 49152, stream);  // zero gq+gk (ws is poisoned 0xAA each call)

    cvt_f32_bf16x8<<<12288, 256, 0, stream>>>(x, xb, (ROWS * KD) / 8);
    transpose_to_bf16<<<dim3(24, 24), 256, 0, stream>>>(Wq, WqT);
    transpose_to_bf16<<<dim3(24, 24), 256, 0, stream>>>(Wk, WkT);
    transpose_to_bf16<<<dim3(24, 24), 256, 0, stream>>>(Wr, WrT);
    cvt_f32_bf16x8<<<288, 256, 0, stream>>>(Wv, Wvb, (KD * KD) / 8);

    gemm_bf16<<<dim3(6, 256), 256, 0, stream>>>(xb, WqT, qk);      // q
    reduce_gq<<<dim3(64, NBATCH), 256, 0, stream>>>(qk, alpha, gq);
    gemm_bf16<<<dim3(6, 256), 256, 0, stream>>>(xb, WkT, qk);      // k (reuses buffer)
    reduce_gk<<<dim3(64, NBATCH), 256, 0, stream>>>(qk, gq, beta, gk);

    scale_wr<<<2304, 256, 0, stream>>>(WrT, gk, WrS);
    gemm_w3<<<dim3(6, 6, NBATCH), 256, 0, stream>>>(WrS, Wvb, Wq, W3T);
    gemm_out_f32<<<dim3(6, 256), 256, 0, stream>>>(xb, W3T, out);
}

// Round 5
// 410.317 us; speedup vs baseline: 1.3782x; 1.3782x over previous
//
#include <hip/hip_runtime.h>
#include <stdint.h>

// FastAttention on MI355X (gfx950).
// Folded algebra:
//   q = x@Wq ; gq[b,d] = sum_n q*softmax_d(q*alpha*scale)
//   k = x@Wk ; p = gq*k ; gk[b,d] = sum_n p*softmax_d(p*beta*scale)
//   out[b] = x[b] @ (Wv @ diag(gk_b) @ Wr + Wq)     <- v / kv never materialized
// GEMM core: 128x128 tile, BK=64, XOR-swizzled LDS (pre-swizzled global src,
// rule #21), XCD-aware block swizzle (T1). bf16 MFMA 16x16x32, fp32 accum.
// Reductions: two-stage (block partials + tiny sum kernel), NO global atomics
// (R2 lesson: 1.57M device-scope atomicAdds onto 6K addresses = 114 us).

#define NBATCH 8
#define SEQ 4096
#define KD 768               // DIM == DEC == 768
#define ROWS (NBATCH * SEQ)  // 32768

typedef __bf16 bf16x8 __attribute__((ext_vector_type(8)));
typedef float f32x4 __attribute__((ext_vector_type(4)));

__device__ __forceinline__ unsigned short f2bf(float f) {
    __bf16 h = (__bf16)f;
    return __builtin_bit_cast(unsigned short, h);
}

__device__ __forceinline__ void gload16(const void* g, void* l) {
    __builtin_amdgcn_global_load_lds((const __attribute__((address_space(1))) void*)g,
                                     (__attribute__((address_space(3))) void*)l, 16, 0, 0);
}

// ---------- conversions ----------

__global__ __launch_bounds__(256) void cvt_f32_bf16x8(const float* __restrict__ src,
                                                      unsigned short* __restrict__ dst, int n8) {
    int i = blockIdx.x * 256 + threadIdx.x;
    if (i >= n8) return;
    const float4* p = (const float4*)src + (size_t)i * 2;
    float4 a = p[0], b = p[1];
    union { unsigned short s[8]; uint4 u; } t;
    t.s[0] = f2bf(a.x); t.s[1] = f2bf(a.y); t.s[2] = f2bf(a.z); t.s[3] = f2bf(a.w);
    t.s[4] = f2bf(b.x); t.s[5] = f2bf(b.y); t.s[6] = f2bf(b.z); t.s[7] = f2bf(b.w);
    ((uint4*)dst)[i] = t.u;
}

// WT[n][k] = bf16(W[k][n]) — 32x32 LDS tile transpose, grid (24,24)
__global__ __launch_bounds__(256) void transpose_to_bf16(const float* __restrict__ W,
                                                         unsigned short* __restrict__ WT) {
    __shared__ float tile[32][33];
    int tx = threadIdx.x & 31, tg = threadIdx.x >> 5;
    int bi = blockIdx.x * 32, bj = blockIdx.y * 32;
#pragma unroll
    for (int j = 0; j < 4; ++j) {
        int r = tg * 4 + j;
        tile[r][tx] = W[(size_t)(bi + r) * KD + bj + tx];
    }
    __syncthreads();
#pragma unroll
    for (int j = 0; j < 4; ++j) {
        int r = tg * 4 + j;
        WT[(size_t)(bj + r) * KD + bi + tx] = f2bf(tile[tx][r]);
    }
}

// ---------- GEMM core: 128x128 tile, BK=64 (128B rows), swizzled LDS ----------

__device__ __forceinline__ void gemm_tile_bk64(const unsigned short* __restrict__ A,
                                               const unsigned short* __restrict__ B,
                                               int m0, int n0, short* sA, short* sB,
                                               f32x4 acc[4][4]) {
    const int tid = threadIdx.x;
    const int lane = tid & 63;
    const int hi = lane >> 4;
    const int wr = (tid >> 7) & 1, wc = (tid >> 6) & 1;
    const f32x4 zero = {0.f, 0.f, 0.f, 0.f};
#pragma unroll
    for (int m = 0; m < 4; ++m)
#pragma unroll
        for (int n = 0; n < 4; ++n) acc[m][n] = zero;

    const int o0 = tid * 16;
    const int srow = o0 >> 7, scb = o0 & 127;
    const int sc = scb ^ ((srow & 7) << 4);  // inverse-swizzled source col
    const char* pA0 = (const char*)A + (size_t)(m0 + srow) * (KD * 2) + sc;
    const char* pB0 = (const char*)B + (size_t)(n0 + srow) * (KD * 2) + sc;
    char* lA0 = (char*)sA + o0;
    char* lB0 = (char*)sB + o0;
    const size_t sstep = (size_t)32 * (KD * 2);  // +32 rows per 4KB LDS chunk

    int offA[4][2], offB[4][2];
#pragma unroll
    for (int m = 0; m < 4; ++m) {
        int rowa = wr * 64 + m * 16 + (lane & 15);
        int rowb = wc * 64 + m * 16 + (lane & 15);
        int swa = (rowa & 7) << 4, swb = (rowb & 7) << 4;
#pragma unroll
        for (int kk = 0; kk < 2; ++kk) {
            offA[m][kk] = rowa * 128 + ((kk * 64 + hi * 16) ^ swa);
            offB[m][kk] = rowb * 128 + ((kk * 64 + hi * 16) ^ swb);
        }
    }

    for (int kt = 0; kt < KD * 2; kt += 128) {  // 12 iterations
        __syncthreads();
#pragma unroll
        for (int s = 0; s < 4; ++s) gload16(pA0 + s * sstep + kt, lA0 + s * 4096);
#pragma unroll
        for (int s = 0; s < 4; ++s) gload16(pB0 + s * sstep + kt, lB0 + s * 4096);
        __syncthreads();
#pragma unroll
        for (int kk = 0; kk < 2; ++kk) {
            bf16x8 af[4], bv[4];
#pragma unroll
            for (int m = 0; m < 4; ++m) af[m] = *(const bf16x8*)((const char*)sA + offA[m][kk]);
#pragma unroll
            for (int n = 0; n < 4; ++n) bv[n] = *(const bf16x8*)((const char*)sB + offB[n][kk]);
#pragma unroll
            for (int m = 0; m < 4; ++m)
#pragma unroll
                for (int n = 0; n < 4; ++n)
                    acc[m][n] = __builtin_amdgcn_mfma_f32_16x16x32_bf16(af[m], bv[n], acc[m][n], 0, 0, 0);
        }
    }
}

// T1: bijective XCD swizzle (nwg % 8 == 0 in all uses)
__device__ __forceinline__ int xcd_swz(int bid, int nwg) {
    int cpx = nwg >> 3;
    return (bid & 7) * cpx + (bid >> 3);
}

// C/D layout (m89): col = lane&15, row = (lane>>4)*4 + reg

__global__ __launch_bounds__(256) void gemm_bf16(const unsigned short* __restrict__ A,
                                                 const unsigned short* __restrict__ B,
                                                 unsigned short* __restrict__ C) {
    __shared__ short sA[128 * 64];
    __shared__ short sB[128 * 64];
    f32x4 acc[4][4];
    int wg = xcd_swz(blockIdx.y * gridDim.x + blockIdx.x, gridDim.x * gridDim.y);
    const int m0 = (wg / gridDim.x) * 128, n0 = (wg % gridDim.x) * 128;
    gemm_tile_bk64(A, B, m0, n0, sA, sB, acc);
    const int lane = threadIdx.x & 63;
    const int wr = (threadIdx.x >> 7) & 1, wc = (threadIdx.x >> 6) & 1;
    const int r0 = m0 + wr * 64 + ((lane >> 4) * 4);
    const int c0 = n0 + wc * 64 + (lane & 15);
#pragma unroll
    for (int m = 0; m < 4; ++m)
#pragma unroll
        for (int n = 0; n < 4; ++n)
#pragma unroll
            for (int r = 0; r < 4; ++r)
                C[(size_t)(r0 + m * 16 + r) * KD + (c0 + n * 16)] = f2bf(acc[m][n][r]);
}

// W3T_b[e][i] = bf16( sum_d WrS_b[e][d]*Wv[i][d] + Wq[i][e] ), grid (6,6,8)
__global__ __launch_bounds__(256) void gemm_w3(const unsigned short* __restrict__ WrS,
                                               const unsigned short* __restrict__ Wvb,
                                               const float* __restrict__ Wq,
                                               unsigned short* __restrict__ W3T) {
    __shared__ short sA[128 * 64];
    __shared__ short sB[128 * 64];
    f32x4 acc[4][4];
    const int b = blockIdx.z;
    const unsigned short* A = WrS + (size_t)b * (KD * KD);
    unsigned short* out = W3T + (size_t)b * (KD * KD);
    const int m0 = blockIdx.y * 128, n0 = blockIdx.x * 128;
    gemm_tile_bk64(A, Wvb, m0, n0, sA, sB, acc);
    const int lane = threadIdx.x & 63;
    const int wr = (threadIdx.x >> 7) & 1, wc = (threadIdx.x >> 6) & 1;
    const int r0 = m0 + wr * 64 + ((lane >> 4) * 4);
    const int c0 = n0 + wc * 64 + (lane & 15);
#pragma unroll
    for (int m = 0; m < 4; ++m)
#pragma unroll
        for (int n = 0; n < 4; ++n)
#pragma unroll
            for (int r = 0; r < 4; ++r) {
                int row = r0 + m * 16 + r, col = c0 + n * 16;
                out[(size_t)row * KD + col] = f2bf(acc[m][n][r] + Wq[(size_t)col * KD + row]);
            }
}

// out[row][e] = sum_i xb[row][i] * W3T_b[e][i], fp32 out, grid (6,256)
__global__ __launch_bounds__(256) void gemm_out_f32(const unsigned short* __restrict__ xb,
                                                    const unsigned short* __restrict__ W3T,
                                                    float* __restrict__ out) {
    __shared__ short sA[128 * 64];
    __shared__ short sB[128 * 64];
    f32x4 acc[4][4];
    int wg = xcd_swz(blockIdx.y * gridDim.x + blockIdx.x, gridDim.x * gridDim.y);
    const int bx = wg % gridDim.x, by = wg / gridDim.x;
    const int m0 = by * 128, n0 = bx * 128;
    const unsigned short* B = W3T + (size_t)(by >> 5) * (KD * KD);  // 32 m-tiles/batch
    gemm_tile_bk64(xb, B, m0, n0, sA, sB, acc);
    const int lane = threadIdx.x & 63;
    const int wr = (threadIdx.x >> 7) & 1, wc = (threadIdx.x >> 6) & 1;
    const int r0 = m0 + wr * 64 + ((lane >> 4) * 4);
    const int c0 = n0 + wc * 64 + (lane & 15);
#pragma unroll
    for (int m = 0; m < 4; ++m)
#pragma unroll
        for (int n = 0; n < 4; ++n)
#pragma unroll
            for (int r = 0; r < 4; ++r)
                out[(size_t)(r0 + m * 16 + r) * KD + (c0 + n * 16)] = acc[m][n][r];
}

// ---------- softmax-weighted reductions: stage 1 (block partials, no atomics) ----------
// lane d map: part1 d = lane*8+j (j<8) covers [0,512); part2 d = 512+lane*4+j (j<4)

#define SM_SCALE 0.03608439182435161f  // 768^-0.5

__device__ __forceinline__ void unpack12(const unsigned short* rowp, int lane, float* q) {
    uint4 u = *(const uint4*)(rowp + lane * 8);
    uint2 v = *(const uint2*)(rowp + 512 + lane * 4);
    q[0] = __uint_as_float(u.x << 16);  q[1] = __uint_as_float(u.x & 0xffff0000u);
    q[2] = __uint_as_float(u.y << 16);  q[3] = __uint_as_float(u.y & 0xffff0000u);
    q[4] = __uint_as_float(u.z << 16);  q[5] = __uint_as_float(u.z & 0xffff0000u);
    q[6] = __uint_as_float(u.w << 16);  q[7] = __uint_as_float(u.w & 0xffff0000u);
    q[8] = __uint_as_float(v.x << 16);  q[9] = __uint_as_float(v.x & 0xffff0000u);
    q[10] = __uint_as_float(v.y << 16); q[11] = __uint_as_float(v.y & 0xffff0000u);
}

__device__ __forceinline__ void load12f(const float* base, int lane, float* o) {
    const float4* p0 = (const float4*)(base + lane * 8);
    float4 x0 = p0[0], x1 = p0[1];
    float4 x2 = *(const float4*)(base + 512 + lane * 4);
    o[0] = x0.x; o[1] = x0.y; o[2] = x0.z; o[3] = x0.w;
    o[4] = x1.x; o[5] = x1.y; o[6] = x1.z; o[7] = x1.w;
    o[8] = x2.x; o[9] = x2.y; o[10] = x2.z; o[11] = x2.w;
}

// write per-lane 12-acc into LDS row, cross-wave sum, one store per block
__device__ __forceinline__ void block_partial_store(float* acc, int lane, int wave,
                                                    float* part_dst) {
    __shared__ float buf[4][KD];
#pragma unroll
    for (int j = 0; j < 8; ++j) buf[wave][lane * 8 + j] = acc[j];
#pragma unroll
    for (int j = 0; j < 4; ++j) buf[wave][512 + lane * 4 + j] = acc[8 + j];
    __syncthreads();
#pragma unroll
    for (int d = threadIdx.x; d < KD; d += 256)
        part_dst[d] = buf[0][d] + buf[1][d] + buf[2][d] + buf[3][d];
}

// grid (64, NBATCH): block = 64 rows (4 waves x 16 rows); part[b][64][768]
__global__ __launch_bounds__(256) void reduce_gq_s1(const unsigned short* __restrict__ qb,
                                                    const float* __restrict__ alpha,
                                                    float* __restrict__ part) {
    const int b = blockIdx.y;
    const int lane = threadIdx.x & 63, wave = threadIdx.x >> 6;
    float al[12];
    load12f(alpha, lane, al);
    float acc[12];
#pragma unroll
    for (int j = 0; j < 12; ++j) acc[j] = 0.f;
    const int row0 = b * SEQ + blockIdx.x * 64 + wave * 16;
#pragma unroll 2
    for (int rr = 0; rr < 16; ++rr) {
        const unsigned short* rowp = qb + (size_t)(row0 + rr) * KD;
        float q[12], t[12];
        unpack12(rowp, lane, q);
        float mx = -1e30f;
#pragma unroll
        for (int j = 0; j < 12; ++j) { t[j] = q[j] * al[j] * SM_SCALE; mx = fmaxf(mx, t[j]); }
#pragma unroll
        for (int s = 32; s > 0; s >>= 1) mx = fmaxf(mx, __shfl_xor(mx, s));
        float sum = 0.f, e[12];
#pragma unroll
        for (int j = 0; j < 12; ++j) { e[j] = __expf(t[j] - mx); sum += e[j]; }
#pragma unroll
        for (int s = 32; s > 0; s >>= 1) sum += __shfl_xor(sum, s);
        float inv = 1.f / sum;
#pragma unroll
        for (int j = 0; j < 12; ++j) acc[j] += q[j] * e[j] * inv;
    }
    block_partial_store(acc, lane, wave, part + ((size_t)b * 64 + blockIdx.x) * KD);
}

__global__ __launch_bounds__(256) void reduce_gk_s1(const unsigned short* __restrict__ kb,
                                                    const float* __restrict__ gq,
                                                    const float* __restrict__ beta,
                                                    float* __restrict__ part) {
    const int b = blockIdx.y;
    const int lane = threadIdx.x & 63, wave = threadIdx.x >> 6;
    float bt[12], gv[12];
    load12f(beta, lane, bt);
    load12f(gq + b * KD, lane, gv);
    float acc[12];
#pragma unroll
    for (int j = 0; j < 12; ++j) acc[j] = 0.f;
    const int row0 = b * SEQ + blockIdx.x * 64 + wave * 16;
#pragma unroll 2
    for (int rr = 0; rr < 16; ++rr) {
        const unsigned short* rowp = kb + (size_t)(row0 + rr) * KD;
        float k[12], p[12], t[12];
        unpack12(rowp, lane, k);
        float mx = -1e30f;
#pragma unroll
        for (int j = 0; j < 12; ++j) {
            p[j] = gv[j] * k[j];
            t[j] = p[j] * bt[j] * SM_SCALE;
            mx = fmaxf(mx, t[j]);
        }
#pragma unroll
        for (int s = 32; s > 0; s >>= 1) mx = fmaxf(mx, __shfl_xor(mx, s));
        float sum = 0.f, e[12];
#pragma unroll
        for (int j = 0; j < 12; ++j) { e[j] = __expf(t[j] - mx); sum += e[j]; }
#pragma unroll
        for (int s = 32; s > 0; s >>= 1) sum += __shfl_xor(sum, s);
        float inv = 1.f / sum;
#pragma unroll
        for (int j = 0; j < 12; ++j) acc[j] += p[j] * e[j] * inv;
    }
    block_partial_store(acc, lane, wave, part + ((size_t)b * 64 + blockIdx.x) * KD);
}

// stage 2: g[b][d] = sum_i part[b][i][d]; grid (3, NBATCH), 256 thr
__global__ __launch_bounds__(256) void reduce_s2(const float* __restrict__ part,
                                                 float* __restrict__ g) {
    const int b = blockIdx.y;
    const int d = blockIdx.x * 256 + threadIdx.x;
    const float* p = part + (size_t)b * 64 * KD + d;
    float s = 0.f;
#pragma unroll 8
    for (int i = 0; i < 64; ++i) s += p[(size_t)i * KD];
    g[b * KD + d] = s;
}

// WrS[b][e][d] = bf16(WrT[e][d] * gk[b][d]); 8 elems/thread, grid 2304
__global__ __launch_bounds__(256) void scale_wr(const unsigned short* __restrict__ WrT,
                                                const float* __restrict__ gk,
                                                unsigned short* __restrict__ WrS) {
    int i = blockIdx.x * 256 + threadIdx.x;  // < 8*73728
    const int per = (KD * KD) / 8;           // 73728
    int b = i / per, g = i % per;
    int d = (g % (KD / 8)) * 8;
    uint4 w = *((const uint4*)WrT + g);
    const float* gkb = gk + b * KD + d;
    float4 s0 = *(const float4*)gkb;
    float4 s1 = *((const float4*)gkb + 1);
    union { unsigned short s[8]; uint4 u; } o;
    o.s[0] = f2bf(__uint_as_float(w.x << 16) * s0.x);
    o.s[1] = f2bf(__uint_as_float(w.x & 0xffff0000u) * s0.y);
    o.s[2] = f2bf(__uint_as_float(w.y << 16) * s0.z);
    o.s[3] = f2bf(__uint_as_float(w.y & 0xffff0000u) * s0.w);
    o.s[4] = f2bf(__uint_as_float(w.z << 16) * s1.x);
    o.s[5] = f2bf(__uint_as_float(w.z & 0xffff0000u) * s1.y);
    o.s[6] = f2bf(__uint_as_float(w.w << 16) * s1.z);
    o.s[7] = f2bf(__uint_as_float(w.w & 0xffff0000u) * s1.w);
    ((uint4*)WrS)[i] = o.u;
}

// ---------- launch ----------

extern "C" void kernel_launch(void* const* d_in, const int* in_sizes, int n_in,
                              void* d_out, int out_size, void* d_ws, size_t ws_size,
                              hipStream_t stream) {
    const float* x     = (const float*)d_in[0];
    const float* Wq    = (const float*)d_in[1];
    const float* Wk    = (const float*)d_in[2];
    const float* Wv    = (const float*)d_in[3];
    const float* Wr    = (const float*)d_in[4];
    const float* alpha = (const float*)d_in[5];
    const float* beta  = (const float*)d_in[6];
    float* out = (float*)d_out;
    char* ws = (char*)d_ws;

    // workspace layout (bytes), total ~124.3 MB (same footprint as passing R1/R2)
    unsigned short* xb  = (unsigned short*)(ws);              // 50,331,648
    unsigned short* qk  = (unsigned short*)(ws + 50331648);   // 50,331,648 (q then reused for k)
    unsigned short* WqT = (unsigned short*)(ws + 100663296);  // 1,179,648
    unsigned short* WkT = (unsigned short*)(ws + 101842944);  // 1,179,648
    unsigned short* WrT = (unsigned short*)(ws + 103022592);  // 1,179,648
    unsigned short* Wvb = (unsigned short*)(ws + 104202240);  // 1,179,648
    unsigned short* WrS = (unsigned short*)(ws + 105381888);  // 9,437,184
    unsigned short* W3T = (unsigned short*)(ws + 114819072);  // 9,437,184
    float* gq = (float*)(ws + 124256256);                     // 24,576
    float* gk = (float*)(ws + 124280832);                     // 24,576
    // partials live in the WrS region (dead until scale_wr): 2 x 1.57 MB
    float* part1 = (float*)(ws + 105381888);
    float* part2 = (float*)(ws + 105381888 + 1572864);

    cvt_f32_bf16x8<<<12288, 256, 0, stream>>>(x, xb, (ROWS * KD) / 8);
    transpose_to_bf16<<<dim3(24, 24), 256, 0, stream>>>(Wq, WqT);
    transpose_to_bf16<<<dim3(24, 24), 256, 0, stream>>>(Wk, WkT);
    transpose_to_bf16<<<dim3(24, 24), 256, 0, stream>>>(Wr, WrT);
    cvt_f32_bf16x8<<<288, 256, 0, stream>>>(Wv, Wvb, (KD * KD) / 8);

    gemm_bf16<<<dim3(6, 256), 256, 0, stream>>>(xb, WqT, qk);      // q
    reduce_gq_s1<<<dim3(64, NBATCH), 256, 0, stream>>>(qk, alpha, part1);
    reduce_s2<<<dim3(3, NBATCH), 256, 0, stream>>>(part1, gq);
    gemm_bf16<<<dim3(6, 256), 256, 0, stream>>>(xb, WkT, qk);      // k (reuses buffer)
    reduce_gk_s1<<<dim3(64, NBATCH), 256, 0, stream>>>(qk, gq, beta, part2);
    reduce_s2<<<dim3(3, NBATCH), 256, 0, stream>>>(part2, gk);

    scale_wr<<<2304, 256, 0, stream>>>(WrT, gk, WrS);
    gemm_w3<<<dim3(6, 6, NBATCH), 256, 0, stream>>>(WrS, Wvb, Wq, W3T);
    gemm_out_f32<<<dim3(6, 256), 256, 0, stream>>>(xb, W3T, out);
}

// Round 6
// 400.078 us; speedup vs baseline: 1.4135x; 1.0256x over previous
//
#include <hip/hip_runtime.h>
#include <stdint.h>

// FastAttention on MI355X (gfx950).
// Folded algebra:
//   q = x@Wq ; gq[b,d] = sum_n q*softmax_d(q*alpha*scale)
//   k = x@Wk ; p = gq*k ; gk[b,d] = sum_n p*softmax_d(p*beta*scale)
//   out[b] = x[b] @ (Wv @ diag(gk_b) @ Wr + Wq)
// R6: big GEMMs on a 3-buffer 2-deep-prefetch pipelined core (T3/T4: counted
// vmcnt(6), never 0 in main loop; raw s_barrier, 1/K-tile) + T2 swizzle
// (now on the critical path) + T5 setprio. q+k merged into one N=1536 GEMM.
// ws_size is 384 MiB (fill evidence R5); we use ~178 MB.

#define NBATCH 8
#define SEQ 4096
#define KD 768
#define ROWS (NBATCH * SEQ)  // 32768
#define NT 12                // K-tiles: 768*2B / 128B

typedef __bf16 bf16x8 __attribute__((ext_vector_type(8)));
typedef float f32x4 __attribute__((ext_vector_type(4)));

__device__ __forceinline__ unsigned short f2bf(float f) {
    __bf16 h = (__bf16)f;
    return __builtin_bit_cast(unsigned short, h);
}

__device__ __forceinline__ void gload16(const void* g, void* l) {
    __builtin_amdgcn_global_load_lds((const __attribute__((address_space(1))) void*)g,
                                     (__attribute__((address_space(3))) void*)l, 16, 0, 0);
}

// ---------- conversions ----------

__global__ __launch_bounds__(256) void cvt_f32_bf16x8(const float* __restrict__ src,
                                                      unsigned short* __restrict__ dst, int n8) {
    int i = blockIdx.x * 256 + threadIdx.x;
    if (i >= n8) return;
    const float4* p = (const float4*)src + (size_t)i * 2;
    float4 a = p[0], b = p[1];
    union { unsigned short s[8]; uint4 u; } t;
    t.s[0] = f2bf(a.x); t.s[1] = f2bf(a.y); t.s[2] = f2bf(a.z); t.s[3] = f2bf(a.w);
    t.s[4] = f2bf(b.x); t.s[5] = f2bf(b.y); t.s[6] = f2bf(b.z); t.s[7] = f2bf(b.w);
    ((uint4*)dst)[i] = t.u;
}

// WT[n][k] = bf16(W[k][n]) — 32x32 LDS tile transpose, grid (24,24)
__global__ __launch_bounds__(256) void transpose_to_bf16(const float* __restrict__ W,
                                                         unsigned short* __restrict__ WT) {
    __shared__ float tile[32][33];
    int tx = threadIdx.x & 31, tg = threadIdx.x >> 5;
    int bi = blockIdx.x * 32, bj = blockIdx.y * 32;
#pragma unroll
    for (int j = 0; j < 4; ++j) {
        int r = tg * 4 + j;
        tile[r][tx] = W[(size_t)(bi + r) * KD + bj + tx];
    }
    __syncthreads();
#pragma unroll
    for (int j = 0; j < 4; ++j) {
        int r = tg * 4 + j;
        WT[(size_t)(bj + r) * KD + bi + tx] = f2bf(tile[tx][r]);
    }
}

// ---------- pipelined GEMM core: BM=256 BN=128 BK=64, 8 waves (4x2), 512 thr ----------
// LDS 144 KB: A 3 x [256][128B], B 3 x [128][128B]; swizzle byte ^= (row&7)<<4
// both sides (rule #21: linear gload_lds dest + inverse-swizzled global src).
// Pipeline: iter t issues stage(t+2); end-of-iter vmcnt(6) retires stage(t+1)
// keeping stage(t+2) in flight across the raw barrier (T4).

template <int LDC, bool F32OUT>
__device__ __forceinline__ void gemm_core(const unsigned short* __restrict__ A,
                                          const unsigned short* __restrict__ Bp,
                                          void* __restrict__ Cout,
                                          int m0, int n0, char* lds) {
    const int tid = threadIdx.x;
    const int lane = tid & 63, wave = tid >> 6;
    const int wr = wave >> 1, wc = wave & 1;   // 4 x 2 wave grid
    const int hi = lane >> 4, lo = lane & 15;
    char* lA = lds;            // 3 * 32768
    char* lB = lds + 98304;    // 3 * 16384

    f32x4 acc[4][4] = {};

    // staging: thread covers 16B at (row0 + 64j, colb); row&7 invariant in j
    const int colb = (tid * 16) & 127;
    const int row0 = tid >> 3;  // 0..63
    const int sc = colb ^ ((row0 & 7) << 4);
    const size_t ldb = (size_t)KD * 2;
    const char* sAg = (const char*)A + (size_t)(m0 + row0) * ldb + sc;
    const char* sBg = (const char*)Bp + (size_t)(n0 + row0) * ldb + sc;

    // fragment LDS byte offsets (swizzled read side); 2-way bank alias = free
    int offA[4][2], offB[4][2];
#pragma unroll
    for (int m = 0; m < 4; ++m) {
        int ra = wr * 64 + m * 16 + lo;
        int rb = wc * 64 + m * 16 + lo;
#pragma unroll
        for (int kk = 0; kk < 2; ++kk) {
            offA[m][kk] = ra * 128 + ((kk * 64 + hi * 16) ^ ((ra & 7) << 4));
            offB[m][kk] = rb * 128 + ((kk * 64 + hi * 16) ^ ((rb & 7) << 4));
        }
    }

#define STAGE(t)                                                              \
    {                                                                         \
        const char* ga = sAg + (t) * 128;                                     \
        const char* gb = sBg + (t) * 128;                                     \
        char* dA = lA + ((t) % 3) * 32768 + tid * 16;                         \
        char* dB = lB + ((t) % 3) * 16384 + tid * 16;                         \
        gload16(ga, dA);                                                      \
        gload16(ga + 64 * ldb, dA + 8192);                                    \
        gload16(ga + 128 * ldb, dA + 16384);                                  \
        gload16(ga + 192 * ldb, dA + 24576);                                  \
        gload16(gb, dB);                                                      \
        gload16(gb + 64 * ldb, dB + 8192);                                    \
    }

    STAGE(0);
    STAGE(1);
    asm volatile("s_waitcnt vmcnt(6)" ::: "memory");  // stage(0) landed (own loads)
    __builtin_amdgcn_s_barrier();                     // all waves vouched
    __builtin_amdgcn_sched_barrier(0);

    for (int t = 0; t < NT; ++t) {
        if (t + 2 < NT) STAGE(t + 2);
        const char* cA = lA + (t % 3) * 32768;
        const char* cB = lB + (t % 3) * 16384;
        bf16x8 af[4][2], bv[4][2];
#pragma unroll
        for (int m = 0; m < 4; ++m)
#pragma unroll
            for (int kk = 0; kk < 2; ++kk) af[m][kk] = *(const bf16x8*)(cA + offA[m][kk]);
#pragma unroll
        for (int n = 0; n < 4; ++n)
#pragma unroll
            for (int kk = 0; kk < 2; ++kk) bv[n][kk] = *(const bf16x8*)(cB + offB[n][kk]);
        __builtin_amdgcn_s_setprio(1);
#pragma unroll
        for (int m = 0; m < 4; ++m)
#pragma unroll
            for (int n = 0; n < 4; ++n)
#pragma unroll
                for (int kk = 0; kk < 2; ++kk)
                    acc[m][n] = __builtin_amdgcn_mfma_f32_16x16x32_bf16(af[m][kk], bv[n][kk],
                                                                        acc[m][n], 0, 0, 0);
        __builtin_amdgcn_s_setprio(0);
        if (t + 2 < NT)
            asm volatile("s_waitcnt vmcnt(6)" ::: "memory");  // retire stage(t+1) only
        else
            asm volatile("s_waitcnt vmcnt(0)" ::: "memory");  // tail drain
        __builtin_amdgcn_s_barrier();
        __builtin_amdgcn_sched_barrier(0);
    }
#undef STAGE

    // C/D layout (m89): col = lane&15, row = hi*4 + reg
    const int r0 = m0 + wr * 64 + hi * 4;
    const int c0 = n0 + wc * 64 + lo;
#pragma unroll
    for (int m = 0; m < 4; ++m)
#pragma unroll
        for (int n = 0; n < 4; ++n)
#pragma unroll
            for (int r = 0; r < 4; ++r) {
                size_t idx = (size_t)(r0 + m * 16 + r) * LDC + (c0 + n * 16);
                if (F32OUT) ((float*)Cout)[idx] = acc[m][n][r];
                else        ((unsigned short*)Cout)[idx] = f2bf(acc[m][n][r]);
            }
}

// T1: bijective XCD swizzle (nwg % 8 == 0 in all uses)
__device__ __forceinline__ int xcd_swz(int bid, int nwg) {
    int cpx = nwg >> 3;
    return (bid & 7) * cpx + (bid >> 3);
}

// q|k merged GEMM: C[32768][1536] bf16, grid (12,128)
__global__ __launch_bounds__(512) void gemm_qk(const unsigned short* __restrict__ xb,
                                               const unsigned short* __restrict__ Wcat,
                                               unsigned short* __restrict__ C) {
    __shared__ char lds[147456];
    int wg = xcd_swz(blockIdx.y * gridDim.x + blockIdx.x, gridDim.x * gridDim.y);
    const int m0 = (wg / 12) * 256, n0 = (wg % 12) * 128;
    gemm_core<1536, false>(xb, Wcat, C, m0, n0, lds);
}

// out[row][e] = sum_i xb[row][i] * W3T_b[e][i], fp32, grid (6,128)
__global__ __launch_bounds__(512) void gemm_out_f32(const unsigned short* __restrict__ xb,
                                                    const unsigned short* __restrict__ W3T,
                                                    float* __restrict__ out) {
    __shared__ char lds[147456];
    int wg = xcd_swz(blockIdx.y * gridDim.x + blockIdx.x, gridDim.x * gridDim.y);
    const int by = wg / 6, bx = wg % 6;
    const unsigned short* Bp = W3T + (size_t)(by >> 4) * (KD * KD);  // 16 m-tiles/batch
    gemm_core<KD, true>(xb, Bp, out, by * 256, bx * 128, lds);
}

// ---------- 128^2 2-phase GEMM (kept for the small W3 fold) ----------

__device__ __forceinline__ void gemm_tile_bk64(const unsigned short* __restrict__ A,
                                               const unsigned short* __restrict__ B,
                                               int m0, int n0, short* sA, short* sB,
                                               f32x4 acc[4][4]) {
    const int tid = threadIdx.x;
    const int lane = tid & 63;
    const int hi = lane >> 4;
    const int wr = (tid >> 7) & 1, wc = (tid >> 6) & 1;
    const f32x4 zero = {0.f, 0.f, 0.f, 0.f};
#pragma unroll
    for (int m = 0; m < 4; ++m)
#pragma unroll
        for (int n = 0; n < 4; ++n) acc[m][n] = zero;

    const int o0 = tid * 16;
    const int srow = o0 >> 7, scb = o0 & 127;
    const int sc = scb ^ ((srow & 7) << 4);
    const char* pA0 = (const char*)A + (size_t)(m0 + srow) * (KD * 2) + sc;
    const char* pB0 = (const char*)B + (size_t)(n0 + srow) * (KD * 2) + sc;
    char* lA0 = (char*)sA + o0;
    char* lB0 = (char*)sB + o0;
    const size_t sstep = (size_t)32 * (KD * 2);

    int offA[4][2], offB[4][2];
#pragma unroll
    for (int m = 0; m < 4; ++m) {
        int rowa = wr * 64 + m * 16 + (lane & 15);
        int rowb = wc * 64 + m * 16 + (lane & 15);
        int swa = (rowa & 7) << 4, swb = (rowb & 7) << 4;
#pragma unroll
        for (int kk = 0; kk < 2; ++kk) {
            offA[m][kk] = rowa * 128 + ((kk * 64 + hi * 16) ^ swa);
            offB[m][kk] = rowb * 128 + ((kk * 64 + hi * 16) ^ swb);
        }
    }

    for (int kt = 0; kt < KD * 2; kt += 128) {
        __syncthreads();
#pragma unroll
        for (int s = 0; s < 4; ++s) gload16(pA0 + s * sstep + kt, lA0 + s * 4096);
#pragma unroll
        for (int s = 0; s < 4; ++s) gload16(pB0 + s * sstep + kt, lB0 + s * 4096);
        __syncthreads();
#pragma unroll
        for (int kk = 0; kk < 2; ++kk) {
            bf16x8 af[4], bv[4];
#pragma unroll
            for (int m = 0; m < 4; ++m) af[m] = *(const bf16x8*)((const char*)sA + offA[m][kk]);
#pragma unroll
            for (int n = 0; n < 4; ++n) bv[n] = *(const bf16x8*)((const char*)sB + offB[n][kk]);
#pragma unroll
            for (int m = 0; m < 4; ++m)
#pragma unroll
                for (int n = 0; n < 4; ++n)
                    acc[m][n] = __builtin_amdgcn_mfma_f32_16x16x32_bf16(af[m], bv[n], acc[m][n], 0, 0, 0);
        }
    }
}

// W3T_b[e][i] = bf16( sum_d WrS_b[e][d]*Wv[i][d] + Wq[i][e] ), grid (6,6,8)
__global__ __launch_bounds__(256) void gemm_w3(const unsigned short* __restrict__ WrS,
                                               const unsigned short* __restrict__ Wvb,
                                               const float* __restrict__ Wq,
                                               unsigned short* __restrict__ W3T) {
    __shared__ short sA[128 * 64];
    __shared__ short sB[128 * 64];
    f32x4 acc[4][4];
    const int b = blockIdx.z;
    const unsigned short* A = WrS + (size_t)b * (KD * KD);
    unsigned short* out = W3T + (size_t)b * (KD * KD);
    const int m0 = blockIdx.y * 128, n0 = blockIdx.x * 128;
    gemm_tile_bk64(A, Wvb, m0, n0, sA, sB, acc);
    const int lane = threadIdx.x & 63;
    const int wr = (threadIdx.x >> 7) & 1, wc = (threadIdx.x >> 6) & 1;
    const int r0 = m0 + wr * 64 + ((lane >> 4) * 4);
    const int c0 = n0 + wc * 64 + (lane & 15);
#pragma unroll
    for (int m = 0; m < 4; ++m)
#pragma unroll
        for (int n = 0; n < 4; ++n)
#pragma unroll
            for (int r = 0; r < 4; ++r) {
                int row = r0 + m * 16 + r, col = c0 + n * 16;
                out[(size_t)row * KD + col] = f2bf(acc[m][n][r] + Wq[(size_t)col * KD + row]);
            }
}

// ---------- softmax-weighted reductions (two-stage, no atomics) ----------
// merged qk buffer: row stride 1536; q = cols [0,768), k = cols [768,1536)

#define SM_SCALE 0.03608439182435161f  // 768^-0.5
#define LDQK 1536

__device__ __forceinline__ void unpack12(const unsigned short* rowp, int lane, float* q) {
    uint4 u = *(const uint4*)(rowp + lane * 8);
    uint2 v = *(const uint2*)(rowp + 512 + lane * 4);
    q[0] = __uint_as_float(u.x << 16);  q[1] = __uint_as_float(u.x & 0xffff0000u);
    q[2] = __uint_as_float(u.y << 16);  q[3] = __uint_as_float(u.y & 0xffff0000u);
    q[4] = __uint_as_float(u.z << 16);  q[5] = __uint_as_float(u.z & 0xffff0000u);
    q[6] = __uint_as_float(u.w << 16);  q[7] = __uint_as_float(u.w & 0xffff0000u);
    q[8] = __uint_as_float(v.x << 16);  q[9] = __uint_as_float(v.x & 0xffff0000u);
    q[10] = __uint_as_float(v.y << 16); q[11] = __uint_as_float(v.y & 0xffff0000u);
}

__device__ __forceinline__ void load12f(const float* base, int lane, float* o) {
    const float4* p0 = (const float4*)(base + lane * 8);
    float4 x0 = p0[0], x1 = p0[1];
    float4 x2 = *(const float4*)(base + 512 + lane * 4);
    o[0] = x0.x; o[1] = x0.y; o[2] = x0.z; o[3] = x0.w;
    o[4] = x1.x; o[5] = x1.y; o[6] = x1.z; o[7] = x1.w;
    o[8] = x2.x; o[9] = x2.y; o[10] = x2.z; o[11] = x2.w;
}

__device__ __forceinline__ void block_partial_store(float* acc, int lane, int wave,
                                                    float* part_dst) {
    __shared__ float buf[4][KD];
#pragma unroll
    for (int j = 0; j < 8; ++j) buf[wave][lane * 8 + j] = acc[j];
#pragma unroll
    for (int j = 0; j < 4; ++j) buf[wave][512 + lane * 4 + j] = acc[8 + j];
    __syncthreads();
#pragma unroll
    for (int d = threadIdx.x; d < KD; d += 256)
        part_dst[d] = buf[0][d] + buf[1][d] + buf[2][d] + buf[3][d];
}

// grid (64, NBATCH): block = 64 rows (4 waves x 16 rows); part[b][64][768]
__global__ __launch_bounds__(256) void reduce_gq_s1(const unsigned short* __restrict__ qk,
                                                    const float* __restrict__ alpha,
                                                    float* __restrict__ part) {
    const int b = blockIdx.y;
    const int lane = threadIdx.x & 63, wave = threadIdx.x >> 6;
    float al[12];
    load12f(alpha, lane, al);
    float acc[12];
#pragma unroll
    for (int j = 0; j < 12; ++j) acc[j] = 0.f;
    const int row0 = b * SEQ + blockIdx.x * 64 + wave * 16;
#pragma unroll 2
    for (int rr = 0; rr < 16; ++rr) {
        const unsigned short* rowp = qk + (size_t)(row0 + rr) * LDQK;
        float q[12], t[12];
        unpack12(rowp, lane, q);
        float mx = -1e30f;
#pragma unroll
        for (int j = 0; j < 12; ++j) { t[j] = q[j] * al[j] * SM_SCALE; mx = fmaxf(mx, t[j]); }
#pragma unroll
        for (int s = 32; s > 0; s >>= 1) mx = fmaxf(mx, __shfl_xor(mx, s));
        float sum = 0.f, e[12];
#pragma unroll
        for (int j = 0; j < 12; ++j) { e[j] = __expf(t[j] - mx); sum += e[j]; }
#pragma unroll
        for (int s = 32; s > 0; s >>= 1) sum += __shfl_xor(sum, s);
        float inv = 1.f / sum;
#pragma unroll
        for (int j = 0; j < 12; ++j) acc[j] += q[j] * e[j] * inv;
    }
    block_partial_store(acc, lane, wave, part + ((size_t)b * 64 + blockIdx.x) * KD);
}

__global__ __launch_bounds__(256) void reduce_gk_s1(const unsigned short* __restrict__ qk,
                                                    const float* __restrict__ gq,
                                                    const float* __restrict__ beta,
                                                    float* __restrict__ part) {
    const int b = blockIdx.y;
    const int lane = threadIdx.x & 63, wave = threadIdx.x >> 6;
    float bt[12], gv[12];
    load12f(beta, lane, bt);
    load12f(gq + b * KD, lane, gv);
    float acc[12];
#pragma unroll
    for (int j = 0; j < 12; ++j) acc[j] = 0.f;
    const int row0 = b * SEQ + blockIdx.x * 64 + wave * 16;
#pragma unroll 2
    for (int rr = 0; rr < 16; ++rr) {
        const unsigned short* rowp = qk + (size_t)(row0 + rr) * LDQK + KD;  // k half
        float k[12], p[12], t[12];
        unpack12(rowp, lane, k);
        float mx = -1e30f;
#pragma unroll
        for (int j = 0; j < 12; ++j) {
            p[j] = gv[j] * k[j];
            t[j] = p[j] * bt[j] * SM_SCALE;
            mx = fmaxf(mx, t[j]);
        }
#pragma unroll
        for (int s = 32; s > 0; s >>= 1) mx = fmaxf(mx, __shfl_xor(mx, s));
        float sum = 0.f, e[12];
#pragma unroll
        for (int j = 0; j < 12; ++j) { e[j] = __expf(t[j] - mx); sum += e[j]; }
#pragma unroll
        for (int s = 32; s > 0; s >>= 1) sum += __shfl_xor(sum, s);
        float inv = 1.f / sum;
#pragma unroll
        for (int j = 0; j < 12; ++j) acc[j] += p[j] * e[j] * inv;
    }
    block_partial_store(acc, lane, wave, part + ((size_t)b * 64 + blockIdx.x) * KD);
}

// stage 2: g[b][d] = sum_i part[b][i][d]; grid (3, NBATCH), 256 thr
__global__ __launch_bounds__(256) void reduce_s2(const float* __restrict__ part,
                                                 float* __restrict__ g) {
    const int b = blockIdx.y;
    const int d = blockIdx.x * 256 + threadIdx.x;
    const float* p = part + (size_t)b * 64 * KD + d;
    float s = 0.f;
#pragma unroll 8
    for (int i = 0; i < 64; ++i) s += p[(size_t)i * KD];
    g[b * KD + d] = s;
}

// WrS[b][e][d] = bf16(WrT[e][d] * gk[b][d]); grid 2304
__global__ __launch_bounds__(256) void scale_wr(const unsigned short* __restrict__ WrT,
                                                const float* __restrict__ gk,
                                                unsigned short* __restrict__ WrS) {
    int i = blockIdx.x * 256 + threadIdx.x;
    const int per = (KD * KD) / 8;
    int b = i / per, g = i % per;
    int d = (g % (KD / 8)) * 8;
    uint4 w = *((const uint4*)WrT + g);
    const float* gkb = gk + b * KD + d;
    float4 s0 = *(const float4*)gkb;
    float4 s1 = *((const float4*)gkb + 1);
    union { unsigned short s[8]; uint4 u; } o;
    o.s[0] = f2bf(__uint_as_float(w.x << 16) * s0.x);
    o.s[1] = f2bf(__uint_as_float(w.x & 0xffff0000u) * s0.y);
    o.s[2] = f2bf(__uint_as_float(w.y << 16) * s0.z);
    o.s[3] = f2bf(__uint_as_float(w.y & 0xffff0000u) * s0.w);
    o.s[4] = f2bf(__uint_as_float(w.z << 16) * s1.x);
    o.s[5] = f2bf(__uint_as_float(w.z & 0xffff0000u) * s1.y);
    o.s[6] = f2bf(__uint_as_float(w.w << 16) * s1.z);
    o.s[7] = f2bf(__uint_as_float(w.w & 0xffff0000u) * s1.w);
    ((uint4*)WrS)[i] = o.u;
}

// ---------- launch ----------

extern "C" void kernel_launch(void* const* d_in, const int* in_sizes, int n_in,
                              void* d_out, int out_size, void* d_ws, size_t ws_size,
                              hipStream_t stream) {
    const float* x     = (const float*)d_in[0];
    const float* Wq    = (const float*)d_in[1];
    const float* Wk    = (const float*)d_in[2];
    const float* Wv    = (const float*)d_in[3];
    const float* Wr    = (const float*)d_in[4];
    const float* alpha = (const float*)d_in[5];
    const float* beta  = (const float*)d_in[6];
    float* out = (float*)d_out;
    char* ws = (char*)d_ws;

    // workspace layout (bytes), total ~178 MB of the 384 MiB ws
    unsigned short* xb   = (unsigned short*)(ws);              //  50,331,648
    unsigned short* qk   = (unsigned short*)(ws + 50331648);   // 100,663,296 ([32768][1536])
    unsigned short* Wcat = (unsigned short*)(ws + 150994944);  //   2,359,296 (WqT|WkT)
    unsigned short* WrT  = (unsigned short*)(ws + 153354240);  //   1,179,648
    unsigned short* Wvb  = (unsigned short*)(ws + 154533888);  //   1,179,648
    unsigned short* WrS  = (unsigned short*)(ws + 155713536);  //   9,437,184
    unsigned short* W3T  = (unsigned short*)(ws + 165150720);  //   9,437,184
    float* gq    = (float*)(ws + 174587904);                   //      24,576
    float* gk    = (float*)(ws + 174612480);                   //      24,576
    float* part1 = (float*)(ws + 174637056);                   //   1,572,864
    float* part2 = (float*)(ws + 176209920);                   //   1,572,864

    cvt_f32_bf16x8<<<12288, 256, 0, stream>>>(x, xb, (ROWS * KD) / 8);
    transpose_to_bf16<<<dim3(24, 24), 256, 0, stream>>>(Wq, Wcat);
    transpose_to_bf16<<<dim3(24, 24), 256, 0, stream>>>(Wk, Wcat + KD * KD);
    transpose_to_bf16<<<dim3(24, 24), 256, 0, stream>>>(Wr, WrT);
    cvt_f32_bf16x8<<<288, 256, 0, stream>>>(Wv, Wvb, (KD * KD) / 8);

    gemm_qk<<<dim3(12, 128), 512, 0, stream>>>(xb, Wcat, qk);  // q|k fused
    reduce_gq_s1<<<dim3(64, NBATCH), 256, 0, stream>>>(qk, alpha, part1);
    reduce_s2<<<dim3(3, NBATCH), 256, 0, stream>>>(part1, gq);
    reduce_gk_s1<<<dim3(64, NBATCH), 256, 0, stream>>>(qk, gq, beta, part2);
    reduce_s2<<<dim3(3, NBATCH), 256, 0, stream>>>(part2, gk);

    scale_wr<<<2304, 256, 0, stream>>>(WrT, gk, WrS);
    gemm_w3<<<dim3(6, 6, NBATCH), 256, 0, stream>>>(WrS, Wvb, Wq, W3T);
    gemm_out_f32<<<dim3(6, 128), 512, 0, stream>>>(xb, W3T, out);
}

// Round 7
// 393.490 us; speedup vs baseline: 1.4372x; 1.0167x over previous
//
#include <hip/hip_runtime.h>
#include <stdint.h>

// FastAttention on MI355X (gfx950).
// Folded algebra:
//   q = x@Wq ; gq[b,d] = sum_n q*softmax_d(q*alpha*scale)
//   k = x@Wk ; p = gq*k ; gk[b,d] = sum_n p*softmax_d(p*beta*scale)
//   out[b] = x[b] @ (Wv @ diag(gk_b) @ Wr + Wq)
// R7: wave-parity kk stagger in the pipelined core (LDS/MFMA pipe overlap);
// dispatch consolidation 12->8 (prep_w merged, s2-gq inlined into gk_s1,
// s2-gk+scale merged); gemm_w3 moved onto the pipelined core (EPI=2).

#define NBATCH 8
#define SEQ 4096
#define KD 768
#define ROWS (NBATCH * SEQ)  // 32768
#define NT 12                // K-tiles: 768*2B / 128B

typedef __bf16 bf16x8 __attribute__((ext_vector_type(8)));
typedef float f32x4 __attribute__((ext_vector_type(4)));

__device__ __forceinline__ unsigned short f2bf(float f) {
    __bf16 h = (__bf16)f;
    return __builtin_bit_cast(unsigned short, h);
}

__device__ __forceinline__ void gload16(const void* g, void* l) {
    __builtin_amdgcn_global_load_lds((const __attribute__((address_space(1))) void*)g,
                                     (__attribute__((address_space(3))) void*)l, 16, 0, 0);
}

// ---------- conversions ----------

__global__ __launch_bounds__(256) void cvt_f32_bf16x8(const float* __restrict__ src,
                                                      unsigned short* __restrict__ dst, int n8) {
    int i = blockIdx.x * 256 + threadIdx.x;
    if (i >= n8) return;
    const float4* p = (const float4*)src + (size_t)i * 2;
    float4 a = p[0], b = p[1];
    union { unsigned short s[8]; uint4 u; } t;
    t.s[0] = f2bf(a.x); t.s[1] = f2bf(a.y); t.s[2] = f2bf(a.z); t.s[3] = f2bf(a.w);
    t.s[4] = f2bf(b.x); t.s[5] = f2bf(b.y); t.s[6] = f2bf(b.z); t.s[7] = f2bf(b.w);
    ((uint4*)dst)[i] = t.u;
}

// merged weight prep: z=0 Wq^T->Wcat, z=1 Wk^T->Wcat+, z=2 Wr^T->WrT, z=3 Wv cvt->Wvb
__global__ __launch_bounds__(256) void prep_w(const float* __restrict__ Wq,
                                              const float* __restrict__ Wk,
                                              const float* __restrict__ Wr,
                                              const float* __restrict__ Wv,
                                              unsigned short* __restrict__ Wcat,
                                              unsigned short* __restrict__ WrT,
                                              unsigned short* __restrict__ Wvb) {
    __shared__ float tile[32][33];
    const int z = blockIdx.z;
    const float* src = (z == 0) ? Wq : (z == 1) ? Wk : (z == 2) ? Wr : Wv;
    unsigned short* dst = (z == 0) ? Wcat : (z == 1) ? (Wcat + KD * KD) : (z == 2) ? WrT : Wvb;
    int tx = threadIdx.x & 31, tg = threadIdx.x >> 5;
    int bi = blockIdx.x * 32, bj = blockIdx.y * 32;
    if (z == 3) {  // straight convert
#pragma unroll
        for (int j = 0; j < 4; ++j) {
            int r = bi + tg * 4 + j;
            dst[(size_t)r * KD + bj + tx] = f2bf(src[(size_t)r * KD + bj + tx]);
        }
        return;
    }
#pragma unroll
    for (int j = 0; j < 4; ++j) {
        int r = tg * 4 + j;
        tile[r][tx] = src[(size_t)(bi + r) * KD + bj + tx];
    }
    __syncthreads();
#pragma unroll
    for (int j = 0; j < 4; ++j) {
        int r = tg * 4 + j;
        dst[(size_t)(bj + r) * KD + bi + tx] = f2bf(tile[tx][r]);
    }
}

// ---------- pipelined GEMM core: BM=256 BN=128 BK=64, 8 waves, 512 thr ----------
// 3-buffer 2-deep prefetch, counted vmcnt(6), raw barrier, T2 swizzle both-sides.
// Wave-parity kk stagger: odd waves process kk=1 first so ds_read bursts of half
// the waves overlap MFMA bursts of the other half (pipe role diversity).
// EPI: 0 = bf16 store, 1 = f32 store, 2 = bf16 store of acc + Wqp[col][row].

template <int LDC, int EPI>
__device__ __forceinline__ void gemm_core(const unsigned short* __restrict__ A,
                                          const unsigned short* __restrict__ Bp,
                                          void* __restrict__ Cout,
                                          const float* __restrict__ Wqp,
                                          int m0, int n0, char* lds) {
    const int tid = threadIdx.x;
    const int lane = tid & 63, wave = tid >> 6;
    const int wr = wave >> 1, wc = wave & 1;   // 4 x 2 wave grid
    const int hi = lane >> 4, lo = lane & 15;
    char* lA = lds;            // 3 * 32768
    char* lB = lds + 98304;    // 3 * 16384

    f32x4 acc[4][4] = {};

    const int colb = (tid * 16) & 127;
    const int row0 = tid >> 3;  // 0..63
    const int sc = colb ^ ((row0 & 7) << 4);
    const size_t ldb = (size_t)KD * 2;
    const char* sAg = (const char*)A + (size_t)(m0 + row0) * ldb + sc;
    const char* sBg = (const char*)Bp + (size_t)(n0 + row0) * ldb + sc;

    // phase-ordered fragment offsets: phase g reads kk = (wave&1)^g. Built with
    // static indices only (rule #20).
    const int kksel = wave & 1;
    int offA[2][4], offB[2][4];
#pragma unroll
    for (int g = 0; g < 2; ++g) {
        const int kkg = kksel ^ g;
#pragma unroll
        for (int m = 0; m < 4; ++m) {
            int ra = wr * 64 + m * 16 + lo;
            int rb = wc * 64 + m * 16 + lo;
            offA[g][m] = ra * 128 + ((kkg * 64 + hi * 16) ^ ((ra & 7) << 4));
            offB[g][m] = rb * 128 + ((kkg * 64 + hi * 16) ^ ((rb & 7) << 4));
        }
    }

#define STAGE(t)                                                              \
    {                                                                         \
        const char* ga = sAg + (t) * 128;                                     \
        const char* gb = sBg + (t) * 128;                                     \
        char* dA = lA + ((t) % 3) * 32768 + tid * 16;                         \
        char* dB = lB + ((t) % 3) * 16384 + tid * 16;                         \
        gload16(ga, dA);                                                      \
        gload16(ga + 64 * ldb, dA + 8192);                                    \
        gload16(ga + 128 * ldb, dA + 16384);                                  \
        gload16(ga + 192 * ldb, dA + 24576);                                  \
        gload16(gb, dB);                                                      \
        gload16(gb + 64 * ldb, dB + 8192);                                    \
    }

    STAGE(0);
    STAGE(1);
    asm volatile("s_waitcnt vmcnt(6)" ::: "memory");  // stage(0) landed (own loads)
    __builtin_amdgcn_s_barrier();
    __builtin_amdgcn_sched_barrier(0);

    for (int t = 0; t < NT; ++t) {
        if (t + 2 < NT) STAGE(t + 2);
        const char* cA = lA + (t % 3) * 32768;
        const char* cB = lB + (t % 3) * 16384;
#pragma unroll
        for (int g = 0; g < 2; ++g) {
            bf16x8 af[4], bv[4];
#pragma unroll
            for (int m = 0; m < 4; ++m) af[m] = *(const bf16x8*)(cA + offA[g][m]);
#pragma unroll
            for (int n = 0; n < 4; ++n) bv[n] = *(const bf16x8*)(cB + offB[g][n]);
            __builtin_amdgcn_s_setprio(1);
#pragma unroll
            for (int m = 0; m < 4; ++m)
#pragma unroll
                for (int n = 0; n < 4; ++n)
                    acc[m][n] = __builtin_amdgcn_mfma_f32_16x16x32_bf16(af[m], bv[n],
                                                                        acc[m][n], 0, 0, 0);
            __builtin_amdgcn_s_setprio(0);
        }
        if (t + 2 < NT)
            asm volatile("s_waitcnt vmcnt(6)" ::: "memory");  // retire stage(t+1) only
        else
            asm volatile("s_waitcnt vmcnt(0)" ::: "memory");  // tail drain
        __builtin_amdgcn_s_barrier();
        __builtin_amdgcn_sched_barrier(0);
    }
#undef STAGE

    // C/D layout (m89): col = lane&15, row = hi*4 + reg
    const int r0 = m0 + wr * 64 + hi * 4;
    const int c0 = n0 + wc * 64 + lo;
#pragma unroll
    for (int m = 0; m < 4; ++m)
#pragma unroll
        for (int n = 0; n < 4; ++n)
#pragma unroll
            for (int r = 0; r < 4; ++r) {
                int row = r0 + m * 16 + r, col = c0 + n * 16;
                size_t idx = (size_t)row * LDC + col;
                if (EPI == 1) {
                    ((float*)Cout)[idx] = acc[m][n][r];
                } else if (EPI == 2) {
                    ((unsigned short*)Cout)[idx] =
                        f2bf(acc[m][n][r] + Wqp[(size_t)col * KD + row]);
                } else {
                    ((unsigned short*)Cout)[idx] = f2bf(acc[m][n][r]);
                }
            }
}

// T1: bijective XCD swizzle (nwg % 8 == 0)
__device__ __forceinline__ int xcd_swz(int bid, int nwg) {
    int cpx = nwg >> 3;
    return (bid & 7) * cpx + (bid >> 3);
}

// q|k merged GEMM: C[32768][1536] bf16, grid (12,128)
__global__ __launch_bounds__(512) void gemm_qk(const unsigned short* __restrict__ xb,
                                               const unsigned short* __restrict__ Wcat,
                                               unsigned short* __restrict__ C) {
    __shared__ char lds[147456];
    int wg = xcd_swz(blockIdx.y * gridDim.x + blockIdx.x, gridDim.x * gridDim.y);
    gemm_core<1536, 0>(xb, Wcat, C, nullptr, (wg / 12) * 256, (wg % 12) * 128, lds);
}

// W3T_b[e][i] = bf16( sum_d WrS_b[e][d]*Wvb[i][d] + Wq[i][e] ), grid (6,3,8)
__global__ __launch_bounds__(512) void gemm_w3(const unsigned short* __restrict__ WrS,
                                               const unsigned short* __restrict__ Wvb,
                                               const float* __restrict__ Wq,
                                               unsigned short* __restrict__ W3T) {
    __shared__ char lds[147456];
    const int b = blockIdx.z;
    gemm_core<KD, 2>(WrS + (size_t)b * (KD * KD), Wvb, W3T + (size_t)b * (KD * KD), Wq,
                     blockIdx.y * 256, blockIdx.x * 128, lds);
}

// out[row][e] = sum_i xb[row][i] * W3T_b[e][i], fp32, grid (6,128)
__global__ __launch_bounds__(512) void gemm_out_f32(const unsigned short* __restrict__ xb,
                                                    const unsigned short* __restrict__ W3T,
                                                    float* __restrict__ out) {
    __shared__ char lds[147456];
    int wg = xcd_swz(blockIdx.y * gridDim.x + blockIdx.x, gridDim.x * gridDim.y);
    const int by = wg / 6, bx = wg % 6;
    const unsigned short* Bp = W3T + (size_t)(by >> 4) * (KD * KD);  // 16 m-tiles/batch
    gemm_core<KD, 1>(xb, Bp, out, nullptr, by * 256, bx * 128, lds);
}

// ---------- softmax-weighted reductions (two-stage, no atomics) ----------
// merged qk buffer: row stride 1536; q = cols [0,768), k = cols [768,1536)

#define SM_SCALE 0.03608439182435161f  // 768^-0.5
#define LDQK 1536

__device__ __forceinline__ void unpack12(const unsigned short* rowp, int lane, float* q) {
    uint4 u = *(const uint4*)(rowp + lane * 8);
    uint2 v = *(const uint2*)(rowp + 512 + lane * 4);
    q[0] = __uint_as_float(u.x << 16);  q[1] = __uint_as_float(u.x & 0xffff0000u);
    q[2] = __uint_as_float(u.y << 16);  q[3] = __uint_as_float(u.y & 0xffff0000u);
    q[4] = __uint_as_float(u.z << 16);  q[5] = __uint_as_float(u.z & 0xffff0000u);
    q[6] = __uint_as_float(u.w << 16);  q[7] = __uint_as_float(u.w & 0xffff0000u);
    q[8] = __uint_as_float(v.x << 16);  q[9] = __uint_as_float(v.x & 0xffff0000u);
    q[10] = __uint_as_float(v.y << 16); q[11] = __uint_as_float(v.y & 0xffff0000u);
}

__device__ __forceinline__ void load12f(const float* base, int lane, float* o) {
    const float4* p0 = (const float4*)(base + lane * 8);
    float4 x0 = p0[0], x1 = p0[1];
    float4 x2 = *(const float4*)(base + 512 + lane * 4);
    o[0] = x0.x; o[1] = x0.y; o[2] = x0.z; o[3] = x0.w;
    o[4] = x1.x; o[5] = x1.y; o[6] = x1.z; o[7] = x1.w;
    o[8] = x2.x; o[9] = x2.y; o[10] = x2.z; o[11] = x2.w;
}

__device__ __forceinline__ void block_partial_store(float* acc, int lane, int wave,
                                                    float* part_dst) {
    __shared__ float buf[4][KD];
#pragma unroll
    for (int j = 0; j < 8; ++j) buf[wave][lane * 8 + j] = acc[j];
#pragma unroll
    for (int j = 0; j < 4; ++j) buf[wave][512 + lane * 4 + j] = acc[8 + j];
    __syncthreads();
#pragma unroll
    for (int d = threadIdx.x; d < KD; d += 256)
        part_dst[d] = buf[0][d] + buf[1][d] + buf[2][d] + buf[3][d];
}

// grid (64, NBATCH): block = 64 rows (4 waves x 16 rows); part1[b][64][768]
__global__ __launch_bounds__(256) void reduce_gq_s1(const unsigned short* __restrict__ qk,
                                                    const float* __restrict__ alpha,
                                                    float* __restrict__ part) {
    const int b = blockIdx.y;
    const int lane = threadIdx.x & 63, wave = threadIdx.x >> 6;
    float al[12];
    load12f(alpha, lane, al);
    float acc[12];
#pragma unroll
    for (int j = 0; j < 12; ++j) acc[j] = 0.f;
    const int row0 = b * SEQ + blockIdx.x * 64 + wave * 16;
#pragma unroll 2
    for (int rr = 0; rr < 16; ++rr) {
        const unsigned short* rowp = qk + (size_t)(row0 + rr) * LDQK;
        float q[12], t[12];
        unpack12(rowp, lane, q);
        float mx = -1e30f;
#pragma unroll
        for (int j = 0; j < 12; ++j) { t[j] = q[j] * al[j] * SM_SCALE; mx = fmaxf(mx, t[j]); }
#pragma unroll
        for (int s = 32; s > 0; s >>= 1) mx = fmaxf(mx, __shfl_xor(mx, s));
        float sum = 0.f, e[12];
#pragma unroll
        for (int j = 0; j < 12; ++j) { e[j] = __expf(t[j] - mx); sum += e[j]; }
#pragma unroll
        for (int s = 32; s > 0; s >>= 1) sum += __shfl_xor(sum, s);
        float inv = 1.f / sum;
#pragma unroll
        for (int j = 0; j < 12; ++j) acc[j] += q[j] * e[j] * inv;
    }
    block_partial_store(acc, lane, wave, part + ((size_t)b * 64 + blockIdx.x) * KD);
}

// gk stage1 with gq stage2 inlined: block sums part1[b] into LDS first.
__global__ __launch_bounds__(256) void reduce_gk_s1(const unsigned short* __restrict__ qk,
                                                    const float* __restrict__ part1,
                                                    const float* __restrict__ beta,
                                                    float* __restrict__ part) {
    __shared__ float sgq[KD];
    const int b = blockIdx.y;
    const int lane = threadIdx.x & 63, wave = threadIdx.x >> 6;
    {
        const float* p = part1 + (size_t)b * 64 * KD;
#pragma unroll
        for (int j = 0; j < 3; ++j) {
            int d = threadIdx.x + j * 256;
            float s = 0.f;
#pragma unroll 8
            for (int i = 0; i < 64; ++i) s += p[(size_t)i * KD + d];
            sgq[d] = s;
        }
    }
    __syncthreads();
    float bt[12], gv[12];
    load12f(beta, lane, bt);
#pragma unroll
    for (int j = 0; j < 8; ++j) gv[j] = sgq[lane * 8 + j];
#pragma unroll
    for (int j = 0; j < 4; ++j) gv[8 + j] = sgq[512 + lane * 4 + j];
    float acc[12];
#pragma unroll
    for (int j = 0; j < 12; ++j) acc[j] = 0.f;
    const int row0 = b * SEQ + blockIdx.x * 64 + wave * 16;
#pragma unroll 2
    for (int rr = 0; rr < 16; ++rr) {
        const unsigned short* rowp = qk + (size_t)(row0 + rr) * LDQK + KD;  // k half
        float k[12], p[12], t[12];
        unpack12(rowp, lane, k);
        float mx = -1e30f;
#pragma unroll
        for (int j = 0; j < 12; ++j) {
            p[j] = gv[j] * k[j];
            t[j] = p[j] * bt[j] * SM_SCALE;
            mx = fmaxf(mx, t[j]);
        }
#pragma unroll
        for (int s = 32; s > 0; s >>= 1) mx = fmaxf(mx, __shfl_xor(mx, s));
        float sum = 0.f, e[12];
#pragma unroll
        for (int j = 0; j < 12; ++j) { e[j] = __expf(t[j] - mx); sum += e[j]; }
#pragma unroll
        for (int s = 32; s > 0; s >>= 1) sum += __shfl_xor(sum, s);
        float inv = 1.f / sum;
#pragma unroll
        for (int j = 0; j < 12; ++j) acc[j] += p[j] * e[j] * inv;
    }
    block_partial_store(acc, lane, wave, part + ((size_t)b * 64 + blockIdx.x) * KD);
}

// merged gk stage2 + scale: grid (24, NBATCH); block = (e-chunk of 32 rows, b).
// Sums part2 -> LDS gk, then WrS[b][e][d] = bf16(WrT[e][d] * gk[d]).
__global__ __launch_bounds__(256) void sum_scale(const float* __restrict__ part2,
                                                 const unsigned short* __restrict__ WrT,
                                                 unsigned short* __restrict__ WrS) {
    __shared__ float sgk[KD];
    const int b = blockIdx.y;
    {
        const float* p = part2 + (size_t)b * 64 * KD;
#pragma unroll
        for (int j = 0; j < 3; ++j) {
            int d = threadIdx.x + j * 256;
            float s = 0.f;
#pragma unroll 8
            for (int i = 0; i < 64; ++i) s += p[(size_t)i * KD + d];
            sgk[d] = s;
        }
    }
    __syncthreads();
    const int e0 = blockIdx.x * 32;
    unsigned short* dst = WrS + (size_t)b * (KD * KD);
    // 32 rows x 96 8-col chunks = 3072 chunks; 12 per thread
#pragma unroll
    for (int c = 0; c < 12; ++c) {
        int idx = c * 256 + threadIdx.x;
        int row = e0 + (idx / 96);
        int col = (idx % 96) * 8;
        uint4 w = *(const uint4*)(WrT + (size_t)row * KD + col);
        union { unsigned short s[8]; uint4 u; } o;
        o.s[0] = f2bf(__uint_as_float(w.x << 16) * sgk[col + 0]);
        o.s[1] = f2bf(__uint_as_float(w.x & 0xffff0000u) * sgk[col + 1]);
        o.s[2] = f2bf(__uint_as_float(w.y << 16) * sgk[col + 2]);
        o.s[3] = f2bf(__uint_as_float(w.y & 0xffff0000u) * sgk[col + 3]);
        o.s[4] = f2bf(__uint_as_float(w.z << 16) * sgk[col + 4]);
        o.s[5] = f2bf(__uint_as_float(w.z & 0xffff0000u) * sgk[col + 5]);
        o.s[6] = f2bf(__uint_as_float(w.w << 16) * sgk[col + 6]);
        o.s[7] = f2bf(__uint_as_float(w.w & 0xffff0000u) * sgk[col + 7]);
        *(uint4*)(dst + (size_t)row * KD + col) = o.u;
    }
}

// ---------- launch ----------

extern "C" void kernel_launch(void* const* d_in, const int* in_sizes, int n_in,
                              void* d_out, int out_size, void* d_ws, size_t ws_size,
                              hipStream_t stream) {
    const float* x     = (const float*)d_in[0];
    const float* Wq    = (const float*)d_in[1];
    const float* Wk    = (const float*)d_in[2];
    const float* Wv    = (const float*)d_in[3];
    const float* Wr    = (const float*)d_in[4];
    const float* alpha = (const float*)d_in[5];
    const float* beta  = (const float*)d_in[6];
    float* out = (float*)d_out;
    char* ws = (char*)d_ws;

    // workspace layout (bytes), ~178 MB of 384 MiB ws (layout proven in R6)
    unsigned short* xb   = (unsigned short*)(ws);              //  50,331,648
    unsigned short* qk   = (unsigned short*)(ws + 50331648);   // 100,663,296 ([32768][1536])
    unsigned short* Wcat = (unsigned short*)(ws + 150994944);  //   2,359,296 (WqT|WkT)
    unsigned short* WrT  = (unsigned short*)(ws + 153354240);  //   1,179,648
    unsigned short* Wvb  = (unsigned short*)(ws + 154533888);  //   1,179,648
    unsigned short* WrS  = (unsigned short*)(ws + 155713536);  //   9,437,184
    unsigned short* W3T  = (unsigned short*)(ws + 165150720);  //   9,437,184
    float* part1 = (float*)(ws + 174637056);                   //   1,572,864
    float* part2 = (float*)(ws + 176209920);                   //   1,572,864

    cvt_f32_bf16x8<<<12288, 256, 0, stream>>>(x, xb, (ROWS * KD) / 8);
    prep_w<<<dim3(24, 24, 4), 256, 0, stream>>>(Wq, Wk, Wr, Wv, Wcat, WrT, Wvb);

    gemm_qk<<<dim3(12, 128), 512, 0, stream>>>(xb, Wcat, qk);  // q|k fused
    reduce_gq_s1<<<dim3(64, NBATCH), 256, 0, stream>>>(qk, alpha, part1);
    reduce_gk_s1<<<dim3(64, NBATCH), 256, 0, stream>>>(qk, part1, beta, part2);

    sum_scale<<<dim3(24, NBATCH), 256, 0, stream>>>(part2, WrT, WrS);
    gemm_w3<<<dim3(6, 3, NBATCH), 512, 0, stream>>>(WrS, Wvb, Wq, W3T);
    gemm_out_f32<<<dim3(6, 128), 512, 0, stream>>>(xb, W3T, out);
}

// Round 8
// 388.032 us; speedup vs baseline: 1.4574x; 1.0141x over previous
//
#include <hip/hip_runtime.h>
#include <stdint.h>

// FastAttention on MI355X (gfx950).
// Folded algebra:
//   q = x@Wq ; gq[b,d] = sum_n q*softmax_d(q*alpha*scale)
//   k = x@Wk ; p = gq*k ; gk[b,d] = sum_n p*softmax_d(p*beta*scale)
//   out[b] = x[b] @ (Wv @ diag(gk_b) @ Wr + Wq)
// R8: 256x256 GEMM core (wave tile 128x64 => 1.5x fewer LDS reads/FLOP),
// 2-slot double buffer 128KB, stage-at-tile-start with whole-tile latency
// cover, no mid-tile barriers (within-wave kk overlap + 2-wave/SIMD drift).
// cvt+prep merged. 7 dispatches.

#define NBATCH 8
#define SEQ 4096
#define KD 768
#define ROWS (NBATCH * SEQ)  // 32768
#define NT 12                // K-tiles: 768*2B / 128B

typedef __bf16 bf16x8 __attribute__((ext_vector_type(8)));
typedef float f32x4 __attribute__((ext_vector_type(4)));

__device__ __forceinline__ unsigned short f2bf(float f) {
    __bf16 h = (__bf16)f;
    return __builtin_bit_cast(unsigned short, h);
}

__device__ __forceinline__ void gload16(const void* g, void* l) {
    __builtin_amdgcn_global_load_lds((const __attribute__((address_space(1))) void*)g,
                                     (__attribute__((address_space(3))) void*)l, 16, 0, 0);
}

// ---------- merged conversions: blocks [0,12288) cvt x; [12288,14592) weight prep ----------

__global__ __launch_bounds__(256) void cvt_prep(const float* __restrict__ x,
                                                const float* __restrict__ Wq,
                                                const float* __restrict__ Wk,
                                                const float* __restrict__ Wr,
                                                const float* __restrict__ Wv,
                                                unsigned short* __restrict__ xb,
                                                unsigned short* __restrict__ Wcat,
                                                unsigned short* __restrict__ WrT,
                                                unsigned short* __restrict__ Wvb) {
    __shared__ float tile[32][33];
    const int bid = blockIdx.x;
    if (bid < 12288) {  // x -> bf16, 8 elems/thread; 12288*256*8 == ROWS*KD exactly
        int i = bid * 256 + threadIdx.x;
        const float4* p = (const float4*)x + (size_t)i * 2;
        float4 a = p[0], b = p[1];
        union { unsigned short s[8]; uint4 u; } t;
        t.s[0] = f2bf(a.x); t.s[1] = f2bf(a.y); t.s[2] = f2bf(a.z); t.s[3] = f2bf(a.w);
        t.s[4] = f2bf(b.x); t.s[5] = f2bf(b.y); t.s[6] = f2bf(b.z); t.s[7] = f2bf(b.w);
        ((uint4*)xb)[i] = t.u;
        return;
    }
    const int idx = bid - 12288;           // 0..2303
    const int z = idx / 576, rem = idx % 576;
    const float* src = (z == 0) ? Wq : (z == 1) ? Wk : (z == 2) ? Wr : Wv;
    unsigned short* dst = (z == 0) ? Wcat : (z == 1) ? (Wcat + KD * KD) : (z == 2) ? WrT : Wvb;
    const int tx = threadIdx.x & 31, tg = threadIdx.x >> 5;
    const int bi = (rem / 24) * 32, bj = (rem % 24) * 32;
    if (z == 3) {  // straight convert
#pragma unroll
        for (int j = 0; j < 4; ++j) {
            int r = bi + tg * 4 + j;
            dst[(size_t)r * KD + bj + tx] = f2bf(src[(size_t)r * KD + bj + tx]);
        }
        return;
    }
#pragma unroll
    for (int j = 0; j < 4; ++j) {
        int r = tg * 4 + j;
        tile[r][tx] = src[(size_t)(bi + r) * KD + bj + tx];
    }
    __syncthreads();
#pragma unroll
    for (int j = 0; j < 4; ++j) {
        int r = tg * 4 + j;
        dst[(size_t)(bj + r) * KD + bi + tx] = f2bf(tile[tx][r]);
    }
}

// ---------- 256x256 GEMM core: BK=64, 8 waves (2m x 4n), wave tile 128x64 ----------
// LDS 128KB: slot s in {0,1} at s*65536: A [256][128B] then B [256][128B].
// Swizzle: byte stored at row*128 + (col ^ ((row&7)<<4)), both sides (rule #21:
// linear gload_lds dest + inverse-swizzled global source + swizzled read addr).
// Per tile t: STAGE(t+1) first (whole tile of compute covers latency), then
// kk0: 12 ds_read_b128 + 32 MFMA, kk1: same (no mid barrier -> wave ILP/drift),
// then vmcnt(0) (stage(t+1) landed; issued ~2500 cyc ago) + barrier.

template <int LDC, int EPI>  // EPI: 0 bf16, 1 f32, 2 bf16 + Wqp[col][row]
__device__ __forceinline__ void gemm_core256(const unsigned short* __restrict__ A,
                                             const unsigned short* __restrict__ Bp,
                                             void* __restrict__ Cout,
                                             const float* __restrict__ Wqp,
                                             int m0, int n0, char* lds) {
    const int tid = threadIdx.x;
    const int lane = tid & 63, wave = tid >> 6;
    const int wr = wave >> 2, wc = wave & 3;   // 2m x 4n wave grid
    const int hi = lane >> 4, lo = lane & 15;

    f32x4 acc[8][4] = {};

    // staging map: thread covers 16B at (row0 + 64j, colb); row&7 invariant in j
    const int colb = (tid & 7) * 16;
    const int row0 = tid >> 3;  // 0..63
    const int sc = colb ^ ((row0 & 7) << 4);
    const size_t ldb = (size_t)KD * 2;
    const char* sAg = (const char*)A + (size_t)(m0 + row0) * ldb + sc;
    const char* sBg = (const char*)Bp + (size_t)(n0 + row0) * ldb + sc;

    // fragment read offsets (swizzled)
    int offA[2][8], offB[2][4];
#pragma unroll
    for (int kk = 0; kk < 2; ++kk) {
#pragma unroll
        for (int m = 0; m < 8; ++m) {
            int ra = wr * 128 + m * 16 + lo;
            offA[kk][m] = ra * 128 + ((kk * 64 + hi * 16) ^ ((ra & 7) << 4));
        }
#pragma unroll
        for (int n = 0; n < 4; ++n) {
            int rb = wc * 64 + n * 16 + lo;
            offB[kk][n] = 32768 + rb * 128 + ((kk * 64 + hi * 16) ^ ((rb & 7) << 4));
        }
    }

#define STAGE(t)                                                              \
    {                                                                         \
        const char* ga = sAg + (t) * 128;                                     \
        const char* gb = sBg + (t) * 128;                                     \
        char* dA = lds + ((t) & 1) * 65536 + tid * 16;                        \
        char* dB = dA + 32768;                                                \
        gload16(ga, dA);                                                      \
        gload16(ga + 64 * ldb, dA + 8192);                                    \
        gload16(ga + 128 * ldb, dA + 16384);                                  \
        gload16(ga + 192 * ldb, dA + 24576);                                  \
        gload16(gb, dB);                                                      \
        gload16(gb + 64 * ldb, dB + 8192);                                    \
        gload16(gb + 128 * ldb, dB + 16384);                                  \
        gload16(gb + 192 * ldb, dB + 24576);                                  \
    }

    STAGE(0);
    asm volatile("s_waitcnt vmcnt(0)" ::: "memory");
    __builtin_amdgcn_s_barrier();
    __builtin_amdgcn_sched_barrier(0);

    for (int t = 0; t < NT; ++t) {
        if (t + 1 < NT) STAGE(t + 1);  // writes slot (t+1)&1, disjoint from reads
        const char* cb = lds + (t & 1) * 65536;
#pragma unroll
        for (int kk = 0; kk < 2; ++kk) {
            bf16x8 af[8], bv[4];
#pragma unroll
            for (int m = 0; m < 8; ++m) af[m] = *(const bf16x8*)(cb + offA[kk][m]);
#pragma unroll
            for (int n = 0; n < 4; ++n) bv[n] = *(const bf16x8*)(cb + offB[kk][n]);
            __builtin_amdgcn_s_setprio(1);
#pragma unroll
            for (int m = 0; m < 8; ++m)
#pragma unroll
                for (int n = 0; n < 4; ++n)
                    acc[m][n] = __builtin_amdgcn_mfma_f32_16x16x32_bf16(af[m], bv[n],
                                                                        acc[m][n], 0, 0, 0);
            __builtin_amdgcn_s_setprio(0);
        }
        if (t + 1 < NT) {
            asm volatile("s_waitcnt vmcnt(0)" ::: "memory");  // stage(t+1) landed
            __builtin_amdgcn_s_barrier();
            __builtin_amdgcn_sched_barrier(0);
        }
    }
#undef STAGE

    // C/D layout (m89): col = lane&15, row = hi*4 + reg
    const int r0 = m0 + wr * 128 + hi * 4;
    const int c0 = n0 + wc * 64 + lo;
#pragma unroll
    for (int m = 0; m < 8; ++m)
#pragma unroll
        for (int n = 0; n < 4; ++n)
#pragma unroll
            for (int r = 0; r < 4; ++r) {
                int row = r0 + m * 16 + r, col = c0 + n * 16;
                size_t idx = (size_t)row * LDC + col;
                if (EPI == 1) {
                    ((float*)Cout)[idx] = acc[m][n][r];
                } else if (EPI == 2) {
                    ((unsigned short*)Cout)[idx] =
                        f2bf(acc[m][n][r] + Wqp[(size_t)col * KD + row]);
                } else {
                    ((unsigned short*)Cout)[idx] = f2bf(acc[m][n][r]);
                }
            }
}

// T1: bijective XCD swizzle (nwg % 8 == 0)
__device__ __forceinline__ int xcd_swz(int bid, int nwg) {
    int cpx = nwg >> 3;
    return (bid & 7) * cpx + (bid >> 3);
}

// q|k merged GEMM: C[32768][1536] bf16, grid (6,128)
__global__ __launch_bounds__(512, 2) void gemm_qk(const unsigned short* __restrict__ xb,
                                                  const unsigned short* __restrict__ Wcat,
                                                  unsigned short* __restrict__ C) {
    __shared__ char lds[131072];
    int wg = xcd_swz(blockIdx.y * gridDim.x + blockIdx.x, gridDim.x * gridDim.y);
    gemm_core256<1536, 0>(xb, Wcat, C, nullptr, (wg / 6) * 256, (wg % 6) * 256, lds);
}

// W3T_b[e][i] = bf16( sum_d WrS_b[e][d]*Wvb[i][d] + Wq[i][e] ), grid (3,3,8)
__global__ __launch_bounds__(512, 2) void gemm_w3(const unsigned short* __restrict__ WrS,
                                                  const unsigned short* __restrict__ Wvb,
                                                  const float* __restrict__ Wq,
                                                  unsigned short* __restrict__ W3T) {
    __shared__ char lds[131072];
    const int b = blockIdx.z;
    gemm_core256<KD, 2>(WrS + (size_t)b * (KD * KD), Wvb, W3T + (size_t)b * (KD * KD), Wq,
                        blockIdx.y * 256, blockIdx.x * 256, lds);
}

// out[row][e] = sum_i xb[row][i] * W3T_b[e][i], fp32, grid (3,128)
__global__ __launch_bounds__(512, 2) void gemm_out_f32(const unsigned short* __restrict__ xb,
                                                       const unsigned short* __restrict__ W3T,
                                                       float* __restrict__ out) {
    __shared__ char lds[131072];
    int wg = xcd_swz(blockIdx.y * gridDim.x + blockIdx.x, gridDim.x * gridDim.y);
    const int by = wg / 3, bx = wg % 3;
    const unsigned short* Bp = W3T + (size_t)(by >> 4) * (KD * KD);  // 16 m-tiles/batch
    gemm_core256<KD, 1>(xb, Bp, out, nullptr, by * 256, bx * 256, lds);
}

// ---------- softmax-weighted reductions (two-stage, no atomics) ----------
// merged qk buffer: row stride 1536; q = cols [0,768), k = cols [768,1536)

#define SM_SCALE 0.03608439182435161f  // 768^-0.5
#define LDQK 1536

__device__ __forceinline__ void unpack12(const unsigned short* rowp, int lane, float* q) {
    uint4 u = *(const uint4*)(rowp + lane * 8);
    uint2 v = *(const uint2*)(rowp + 512 + lane * 4);
    q[0] = __uint_as_float(u.x << 16);  q[1] = __uint_as_float(u.x & 0xffff0000u);
    q[2] = __uint_as_float(u.y << 16);  q[3] = __uint_as_float(u.y & 0xffff0000u);
    q[4] = __uint_as_float(u.z << 16);  q[5] = __uint_as_float(u.z & 0xffff0000u);
    q[6] = __uint_as_float(u.w << 16);  q[7] = __uint_as_float(u.w & 0xffff0000u);
    q[8] = __uint_as_float(v.x << 16);  q[9] = __uint_as_float(v.x & 0xffff0000u);
    q[10] = __uint_as_float(v.y << 16); q[11] = __uint_as_float(v.y & 0xffff0000u);
}

__device__ __forceinline__ void load12f(const float* base, int lane, float* o) {
    const float4* p0 = (const float4*)(base + lane * 8);
    float4 x0 = p0[0], x1 = p0[1];
    float4 x2 = *(const float4*)(base + 512 + lane * 4);
    o[0] = x0.x; o[1] = x0.y; o[2] = x0.z; o[3] = x0.w;
    o[4] = x1.x; o[5] = x1.y; o[6] = x1.z; o[7] = x1.w;
    o[8] = x2.x; o[9] = x2.y; o[10] = x2.z; o[11] = x2.w;
}

__device__ __forceinline__ void block_partial_store(float* acc, int lane, int wave,
                                                    float* part_dst) {
    __shared__ float buf[4][KD];
#pragma unroll
    for (int j = 0; j < 8; ++j) buf[wave][lane * 8 + j] = acc[j];
#pragma unroll
    for (int j = 0; j < 4; ++j) buf[wave][512 + lane * 4 + j] = acc[8 + j];
    __syncthreads();
#pragma unroll
    for (int d = threadIdx.x; d < KD; d += 256)
        part_dst[d] = buf[0][d] + buf[1][d] + buf[2][d] + buf[3][d];
}

// grid (64, NBATCH): block = 64 rows (4 waves x 16 rows); part1[b][64][768]
__global__ __launch_bounds__(256) void reduce_gq_s1(const unsigned short* __restrict__ qk,
                                                    const float* __restrict__ alpha,
                                                    float* __restrict__ part) {
    const int b = blockIdx.y;
    const int lane = threadIdx.x & 63, wave = threadIdx.x >> 6;
    float al[12];
    load12f(alpha, lane, al);
    float acc[12];
#pragma unroll
    for (int j = 0; j < 12; ++j) acc[j] = 0.f;
    const int row0 = b * SEQ + blockIdx.x * 64 + wave * 16;
#pragma unroll 2
    for (int rr = 0; rr < 16; ++rr) {
        const unsigned short* rowp = qk + (size_t)(row0 + rr) * LDQK;
        float q[12], t[12];
        unpack12(rowp, lane, q);
        float mx = -1e30f;
#pragma unroll
        for (int j = 0; j < 12; ++j) { t[j] = q[j] * al[j] * SM_SCALE; mx = fmaxf(mx, t[j]); }
#pragma unroll
        for (int s = 32; s > 0; s >>= 1) mx = fmaxf(mx, __shfl_xor(mx, s));
        float sum = 0.f, e[12];
#pragma unroll
        for (int j = 0; j < 12; ++j) { e[j] = __expf(t[j] - mx); sum += e[j]; }
#pragma unroll
        for (int s = 32; s > 0; s >>= 1) sum += __shfl_xor(sum, s);
        float inv = 1.f / sum;
#pragma unroll
        for (int j = 0; j < 12; ++j) acc[j] += q[j] * e[j] * inv;
    }
    block_partial_store(acc, lane, wave, part + ((size_t)b * 64 + blockIdx.x) * KD);
}

// gk stage1 with gq stage2 inlined: block sums part1[b] into LDS first.
__global__ __launch_bounds__(256) void reduce_gk_s1(const unsigned short* __restrict__ qk,
                                                    const float* __restrict__ part1,
                                                    const float* __restrict__ beta,
                                                    float* __restrict__ part) {
    __shared__ float sgq[KD];
    const int b = blockIdx.y;
    const int lane = threadIdx.x & 63, wave = threadIdx.x >> 6;
    {
        const float* p = part1 + (size_t)b * 64 * KD;
#pragma unroll
        for (int j = 0; j < 3; ++j) {
            int d = threadIdx.x + j * 256;
            float s = 0.f;
#pragma unroll 8
            for (int i = 0; i < 64; ++i) s += p[(size_t)i * KD + d];
            sgq[d] = s;
        }
    }
    __syncthreads();
    float bt[12], gv[12];
    load12f(beta, lane, bt);
#pragma unroll
    for (int j = 0; j < 8; ++j) gv[j] = sgq[lane * 8 + j];
#pragma unroll
    for (int j = 0; j < 4; ++j) gv[8 + j] = sgq[512 + lane * 4 + j];
    float acc[12];
#pragma unroll
    for (int j = 0; j < 12; ++j) acc[j] = 0.f;
    const int row0 = b * SEQ + blockIdx.x * 64 + wave * 16;
#pragma unroll 2
    for (int rr = 0; rr < 16; ++rr) {
        const unsigned short* rowp = qk + (size_t)(row0 + rr) * LDQK + KD;  // k half
        float k[12], p[12], t[12];
        unpack12(rowp, lane, k);
        float mx = -1e30f;
#pragma unroll
        for (int j = 0; j < 12; ++j) {
            p[j] = gv[j] * k[j];
            t[j] = p[j] * bt[j] * SM_SCALE;
            mx = fmaxf(mx, t[j]);
        }
#pragma unroll
        for (int s = 32; s > 0; s >>= 1) mx = fmaxf(mx, __shfl_xor(mx, s));
        float sum = 0.f, e[12];
#pragma unroll
        for (int j = 0; j < 12; ++j) { e[j] = __expf(t[j] - mx); sum += e[j]; }
#pragma unroll
        for (int s = 32; s > 0; s >>= 1) sum += __shfl_xor(sum, s);
        float inv = 1.f / sum;
#pragma unroll
        for (int j = 0; j < 12; ++j) acc[j] += p[j] * e[j] * inv;
    }
    block_partial_store(acc, lane, wave, part + ((size_t)b * 64 + blockIdx.x) * KD);
}

// merged gk stage2 + scale: grid (24, NBATCH).
__global__ __launch_bounds__(256) void sum_scale(const float* __restrict__ part2,
                                                 const unsigned short* __restrict__ WrT,
                                                 unsigned short* __restrict__ WrS) {
    __shared__ float sgk[KD];
    const int b = blockIdx.y;
    {
        const float* p = part2 + (size_t)b * 64 * KD;
#pragma unroll
        for (int j = 0; j < 3; ++j) {
            int d = threadIdx.x + j * 256;
            float s = 0.f;
#pragma unroll 8
            for (int i = 0; i < 64; ++i) s += p[(size_t)i * KD + d];
            sgk[d] = s;
        }
    }
    __syncthreads();
    const int e0 = blockIdx.x * 32;
    unsigned short* dst = WrS + (size_t)b * (KD * KD);
#pragma unroll
    for (int c = 0; c < 12; ++c) {
        int idx = c * 256 + threadIdx.x;
        int row = e0 + (idx / 96);
        int col = (idx % 96) * 8;
        uint4 w = *(const uint4*)(WrT + (size_t)row * KD + col);
        union { unsigned short s[8]; uint4 u; } o;
        o.s[0] = f2bf(__uint_as_float(w.x << 16) * sgk[col + 0]);
        o.s[1] = f2bf(__uint_as_float(w.x & 0xffff0000u) * sgk[col + 1]);
        o.s[2] = f2bf(__uint_as_float(w.y << 16) * sgk[col + 2]);
        o.s[3] = f2bf(__uint_as_float(w.y & 0xffff0000u) * sgk[col + 3]);
        o.s[4] = f2bf(__uint_as_float(w.z << 16) * sgk[col + 4]);
        o.s[5] = f2bf(__uint_as_float(w.z & 0xffff0000u) * sgk[col + 5]);
        o.s[6] = f2bf(__uint_as_float(w.w << 16) * sgk[col + 6]);
        o.s[7] = f2bf(__uint_as_float(w.w & 0xffff0000u) * sgk[col + 7]);
        *(uint4*)(dst + (size_t)row * KD + col) = o.u;
    }
}

// ---------- launch ----------

extern "C" void kernel_launch(void* const* d_in, const int* in_sizes, int n_in,
                              void* d_out, int out_size, void* d_ws, size_t ws_size,
                              hipStream_t stream) {
    const float* x     = (const float*)d_in[0];
    const float* Wq    = (const float*)d_in[1];
    const float* Wk    = (const float*)d_in[2];
    const float* Wr    = (const float*)d_in[3 - 1];  // keep explicit order below
    const float* Wv    = (const float*)d_in[3];
    const float* Wr_   = (const float*)d_in[4];
    const float* alpha = (const float*)d_in[5];
    const float* beta  = (const float*)d_in[6];
    (void)Wr;
    float* out = (float*)d_out;
    char* ws = (char*)d_ws;

    // workspace layout (bytes), ~178 MB of 384 MiB ws (layout proven R6/R7)
    unsigned short* xb   = (unsigned short*)(ws);              //  50,331,648
    unsigned short* qk   = (unsigned short*)(ws + 50331648);   // 100,663,296 ([32768][1536])
    unsigned short* Wcat = (unsigned short*)(ws + 150994944);  //   2,359,296 (WqT|WkT)
    unsigned short* WrT  = (unsigned short*)(ws + 153354240);  //   1,179,648
    unsigned short* Wvb  = (unsigned short*)(ws + 154533888);  //   1,179,648
    unsigned short* WrS  = (unsigned short*)(ws + 155713536);  //   9,437,184
    unsigned short* W3T  = (unsigned short*)(ws + 165150720);  //   9,437,184
    float* part1 = (float*)(ws + 174637056);                   //   1,572,864
    float* part2 = (float*)(ws + 176209920);                   //   1,572,864

    cvt_prep<<<14592, 256, 0, stream>>>(x, Wq, Wk, Wr_, Wv, xb, Wcat, WrT, Wvb);

    gemm_qk<<<dim3(6, 128), 512, 0, stream>>>(xb, Wcat, qk);  // q|k fused
    reduce_gq_s1<<<dim3(64, NBATCH), 256, 0, stream>>>(qk, alpha, part1);
    reduce_gk_s1<<<dim3(64, NBATCH), 256, 0, stream>>>(qk, part1, beta, part2);

    sum_scale<<<dim3(24, NBATCH), 256, 0, stream>>>(part2, WrT, WrS);
    gemm_w3<<<dim3(3, 3, NBATCH), 512, 0, stream>>>(WrS, Wvb, Wq, W3T);
    gemm_out_f32<<<dim3(3, 128), 512, 0, stream>>>(xb, W3T, out);
}